// Round 1
// baseline (2914.764 us; speedup 1.0000x reference)
//
#include <hip/hip_runtime.h>

typedef unsigned short u16;
typedef unsigned int u32;
typedef __attribute__((ext_vector_type(8))) short short8;
typedef __attribute__((ext_vector_type(4))) float f4;

#define DEV static __device__ __forceinline__

constexpr int BB = 16, NN = 2048, DD = 1024, HH = 8, DHD = 64, II = 512, LL = 64, DEPTHC = 6, FFC = 4096;

DEV u16 f2bf(float f) {
  union { float f; u32 u; } v; v.f = f;
  u32 r = v.u + 0x7FFFu + ((v.u >> 16) & 1u);
  return (u16)(r >> 16);
}

typedef const u32 __attribute__((address_space(1)))* gas_p;
typedef u32 __attribute__((address_space(3)))* las_p;
DEV void gl_lds16(const void* g, void* l) {
  __builtin_amdgcn_global_load_lds((gas_p)g, (las_p)l, 16, 0, 0);
}

// ---------------- LayerNorm over rows of 1024 ----------------
template<bool OUTF32, bool AFFINE>
__global__ __launch_bounds__(256) void ln_rows_k(const float* __restrict__ in,
    const float* __restrict__ w, const float* __restrict__ bias, void* __restrict__ out) {
  int row = blockIdx.x;
  int tid = threadIdx.x;
  const float4* rp = (const float4*)(in + (size_t)row * DD);
  float4 x = rp[tid];
  float s = x.x + x.y + x.z + x.w;
  float s2 = x.x*x.x + x.y*x.y + x.z*x.z + x.w*x.w;
  #pragma unroll
  for (int off = 32; off >= 1; off >>= 1) {
    s  += __shfl_xor(s, off, 64);
    s2 += __shfl_xor(s2, off, 64);
  }
  __shared__ float red[8];
  int wv = tid >> 6;
  if ((tid & 63) == 0) { red[wv] = s; red[4 + wv] = s2; }
  __syncthreads();
  s  = red[0] + red[1] + red[2] + red[3];
  s2 = red[4] + red[5] + red[6] + red[7];
  float mu = s * (1.f / DD);
  float var = s2 * (1.f / DD) - mu * mu;
  float rstd = rsqrtf(var + 1e-5f);
  float y[4] = {x.x, x.y, x.z, x.w};
  int col = tid * 4;
  #pragma unroll
  for (int j = 0; j < 4; j++) {
    float v = (y[j] - mu) * rstd;
    if (AFFINE) v = v * w[col + j] + bias[col + j];
    y[j] = v;
  }
  if (OUTF32) {
    float4 o = {y[0], y[1], y[2], y[3]};
    ((float4*)out)[(size_t)row * (DD/4) + tid] = o;
  } else {
    ushort4 o = make_ushort4(f2bf(y[0]), f2bf(y[1]), f2bf(y[2]), f2bf(y[3]));
    ((ushort4*)out)[(size_t)row * (DD/4) + tid] = o;
  }
}

// ---------------- lat init: broadcast latents over batch ----------------
__global__ __launch_bounds__(256) void lat_init_k(const float* __restrict__ latents, float* __restrict__ lat) {
  int idx = blockIdx.x * 256 + threadIdx.x;
  ((float4*)lat)[idx] = ((const float4*)latents)[idx & (LL * DD / 4 - 1)];
}

// ---------------- transpose fp32 [R][C] -> bf16 [C][R]; optional scaled copy ----------------
__global__ void transp_k(const float* __restrict__ in, u16* __restrict__ outp,
                         u16* __restrict__ outs, const float* __restrict__ scale, int R, int C) {
  __shared__ float t[32][33];
  int c0 = blockIdx.x * 32, r0 = blockIdx.y * 32;
  int tx = threadIdx.x, ty = threadIdx.y; // 32 x 8
  #pragma unroll
  for (int j = 0; j < 4; j++)
    t[ty + j*8][tx] = in[(size_t)(r0 + ty + j*8) * C + c0 + tx];
  __syncthreads();
  float sc = scale ? scale[r0 + tx] : 1.f;
  #pragma unroll
  for (int j = 0; j < 4; j++) {
    float v = t[tx][ty + j*8];
    size_t o = (size_t)(c0 + ty + j*8) * R + r0 + tx;
    if (outp) outp[o] = f2bf(v);
    if (outs) outs[o] = f2bf(v * sc);
  }
}

// ---------------- bias row: out[j] = sum_d b[d] * W[d][j] ----------------
__global__ __launch_bounds__(256) void biascol_k(const float* __restrict__ bvec,
    const float* __restrict__ W, float* __restrict__ out, int Drows, int Ncols) {
  int j = blockIdx.x * 256 + threadIdx.x;
  float a = 0.f;
  #pragma unroll 8
  for (int d = 0; d < Drows; d++) a += bvec[d] * W[(size_t)d * Ncols + j];
  out[j] = a;
}

// ---------------- GEMM: C[M,N] = A[M,K](bf16) @ Bm[N,K](bf16)^T ----------------
// EPI: 0 = bf16 out, 1 = bf16 + bias[col], 2 = bf16 gelu(exact), 3 = f32 out + resid
template<int EPI>
__global__ __launch_bounds__(256) void gemm_k(const u16* __restrict__ A, const u16* __restrict__ Bm,
    void* __restrict__ C, const float* __restrict__ bias, const float* __restrict__ resid,
    int M, int N, int K) {
  __shared__ __align__(16) u16 As[128 * 32];
  __shared__ __align__(16) u16 Bs[128 * 32];
  int tid = threadIdx.x;
  int wv = tid >> 6, lane = tid & 63;
  int m0 = blockIdx.y * 128, n0 = blockIdx.x * 128;
  int srow = wv * 16 + (lane >> 2);
  int scol = (lane & 3) * 8;
  const u16* gA0 = A + (size_t)(m0 + srow) * K + scol;
  const u16* gA1 = A + (size_t)(m0 + 64 + srow) * K + scol;
  const u16* gB0 = Bm + (size_t)(n0 + srow) * K + scol;
  const u16* gB1 = Bm + (size_t)(n0 + 64 + srow) * K + scol;
  u16* lA0 = &As[srow * 32 + scol];
  u16* lA1 = &As[(64 + srow) * 32 + scol];
  u16* lB0 = &Bs[srow * 32 + scol];
  u16* lB1 = &Bs[(64 + srow) * 32 + scol];
  int wm = (wv & 1) * 64, wn = (wv >> 1) * 64;
  int fr = lane & 15, fq = (lane >> 4) * 8;
  f4 acc[4][4];
  #pragma unroll
  for (int mi = 0; mi < 4; mi++)
    #pragma unroll
    for (int ni = 0; ni < 4; ni++) acc[mi][ni] = f4{0.f, 0.f, 0.f, 0.f};

  for (int k0 = 0; k0 < K; k0 += 32) {
    gl_lds16(gA0 + k0, lA0);
    gl_lds16(gA1 + k0, lA1);
    gl_lds16(gB0 + k0, lB0);
    gl_lds16(gB1 + k0, lB1);
    __syncthreads();
    short8 af[4], bfr[4];
    #pragma unroll
    for (int mi = 0; mi < 4; mi++)
      af[mi] = *(const short8*)&As[(wm + mi*16 + fr) * 32 + fq];
    #pragma unroll
    for (int ni = 0; ni < 4; ni++)
      bfr[ni] = *(const short8*)&Bs[(wn + ni*16 + fr) * 32 + fq];
    #pragma unroll
    for (int mi = 0; mi < 4; mi++)
      #pragma unroll
      for (int ni = 0; ni < 4; ni++)
        acc[mi][ni] = __builtin_amdgcn_mfma_f32_16x16x32_bf16(af[mi], bfr[ni], acc[mi][ni], 0, 0, 0);
    __syncthreads();
  }
  int er = (lane >> 4) * 4;
  int ec = lane & 15;
  #pragma unroll
  for (int mi = 0; mi < 4; mi++) {
    #pragma unroll
    for (int ni = 0; ni < 4; ni++) {
      int col = n0 + wn + ni*16 + ec;
      #pragma unroll
      for (int r = 0; r < 4; r++) {
        int row = m0 + wm + mi*16 + er + r;
        float v = acc[mi][ni][r];
        if (EPI == 1) v += bias[col];
        if (EPI == 2) v = 0.5f * v * (1.f + erff(v * 0.70710678118654752f));
        size_t off = (size_t)row * N + col;
        if (EPI == 3) ((float*)C)[off] = v + resid[off];
        else          ((u16*)C)[off] = f2bf(v);
      }
    }
  }
}

// ---------------- flash attention: one block per (b,h), 33 key tiles of 64 ----------------
__global__ __launch_bounds__(256) void attn_k(const u16* __restrict__ q,
    const u16* __restrict__ kv_x, const u16* __restrict__ kv_lat,
    const int* __restrict__ mask, u16* __restrict__ out) {
  int b = blockIdx.x >> 3;
  int h = blockIdx.x & 7;
  int tid = threadIdx.x;
  int wv = tid >> 6, lane = tid & 63;
  int fr = lane & 15, fq8 = (lane >> 4) * 8;

  __shared__ __align__(16) u16 ks[64 * 88];     // k tile [key][d], pad->88
  __shared__ __align__(16) u16 vs[64 * 88];     // v tile transposed [d][key]
  __shared__ __align__(16) u16 ps[4][16 * 88];  // per-wave P round-trip
  __shared__ float smask[64];

  const u16* qp = q + (size_t)(b * LL + wv * 16 + fr) * II + h * DHD;
  short8 aq0 = *(const short8*)(qp + fq8);
  short8 aq1 = *(const short8*)(qp + 32 + fq8);

  float m_i[4], l_i[4];
  f4 o[4];
  #pragma unroll
  for (int r = 0; r < 4; r++) { m_i[r] = -1e30f; l_i[r] = 0.f; }
  #pragma unroll
  for (int dt = 0; dt < 4; dt++) o[dt] = f4{0.f, 0.f, 0.f, 0.f};

  const float scale = 0.125f; // DH^-0.5

  for (int t = 0; t < 33; t++) {
    __syncthreads();
    const u16* src = (t < 32) ? (kv_x + ((size_t)(b * NN + t * 64)) * 1024 + h * DHD)
                              : (kv_lat + ((size_t)(b * LL)) * 1024 + h * DHD);
    #pragma unroll
    for (int it = 0; it < 2; it++) {
      int cid = it * 256 + tid;       // 512 chunks of 8 elems over 64x64
      int kr = cid >> 3, c8 = (cid & 7) * 8;
      int4 kvv = *(const int4*)(src + (size_t)kr * 1024 + c8);
      *(int4*)&ks[kr * 88 + c8] = kvv;
      int4 vvv = *(const int4*)(src + II + (size_t)kr * 1024 + c8);
      const u16* ve = (const u16*)&vvv;
      #pragma unroll
      for (int j = 0; j < 8; j++) vs[(c8 + j) * 88 + kr] = ve[j];
    }
    if (tid < 64)
      smask[tid] = (t < 32 && mask[b * NN + t * 64 + tid] != 0) ? -1e30f : 0.f;
    __syncthreads();

    // sim = q @ k^T for this wave's 16 q rows x 64 keys
    f4 sim[4];
    #pragma unroll
    for (int ct = 0; ct < 4; ct++) {
      short8 b0 = *(const short8*)&ks[(ct*16 + fr) * 88 + fq8];
      short8 b1 = *(const short8*)&ks[(ct*16 + fr) * 88 + 32 + fq8];
      f4 s = f4{0.f, 0.f, 0.f, 0.f};
      s = __builtin_amdgcn_mfma_f32_16x16x32_bf16(aq0, b0, s, 0, 0, 0);
      s = __builtin_amdgcn_mfma_f32_16x16x32_bf16(aq1, b1, s, 0, 0, 0);
      float mk = smask[ct*16 + fr];
      #pragma unroll
      for (int r = 0; r < 4; r++) s[r] = s[r] * scale + mk;
      sim[ct] = s;
    }
    // online softmax (rows live in quads; 16 lanes/quad hold 16 cols)
    float mnew[4], alpha[4], p[4][4];
    #pragma unroll
    for (int r = 0; r < 4; r++) {
      float mx = fmaxf(fmaxf(sim[0][r], sim[1][r]), fmaxf(sim[2][r], sim[3][r]));
      #pragma unroll
      for (int off = 8; off >= 1; off >>= 1) mx = fmaxf(mx, __shfl_xor(mx, off, 16));
      mnew[r] = fmaxf(m_i[r], mx);
      alpha[r] = __expf(m_i[r] - mnew[r]);
      m_i[r] = mnew[r];
      float ssum = 0.f;
      #pragma unroll
      for (int ct = 0; ct < 4; ct++) { float e = __expf(sim[ct][r] - mnew[r]); p[ct][r] = e; ssum += e; }
      #pragma unroll
      for (int off = 8; off >= 1; off >>= 1) ssum += __shfl_xor(ssum, off, 16);
      l_i[r] = l_i[r] * alpha[r] + ssum;
    }
    // P (C layout) -> LDS -> A layout
    #pragma unroll
    for (int ct = 0; ct < 4; ct++)
      #pragma unroll
      for (int r = 0; r < 4; r++)
        ps[wv][((lane>>4)*4 + r) * 88 + ct*16 + fr] = f2bf(p[ct][r]);
    #pragma unroll
    for (int dt = 0; dt < 4; dt++)
      #pragma unroll
      for (int r = 0; r < 4; r++) o[dt][r] *= alpha[r];
    short8 pa0 = *(const short8*)&ps[wv][fr * 88 + fq8];
    short8 pa1 = *(const short8*)&ps[wv][fr * 88 + 32 + fq8];
    #pragma unroll
    for (int dt = 0; dt < 4; dt++) {
      short8 bv0 = *(const short8*)&vs[(dt*16 + fr) * 88 + fq8];
      short8 bv1 = *(const short8*)&vs[(dt*16 + fr) * 88 + 32 + fq8];
      o[dt] = __builtin_amdgcn_mfma_f32_16x16x32_bf16(pa0, bv0, o[dt], 0, 0, 0);
      o[dt] = __builtin_amdgcn_mfma_f32_16x16x32_bf16(pa1, bv1, o[dt], 0, 0, 0);
    }
  }
  #pragma unroll
  for (int dt = 0; dt < 4; dt++)
    #pragma unroll
    for (int r = 0; r < 4; r++) {
      int row = b * LL + wv * 16 + (lane>>4)*4 + r;
      int col = h * DHD + dt*16 + fr;
      out[(size_t)row * II + col] = f2bf(o[dt][r] / l_i[r]);
    }
}

extern "C" void kernel_launch(void* const* d_in, const int* in_sizes, int n_in,
                              void* d_out, int out_size, void* d_ws, size_t ws_size,
                              hipStream_t stream) {
  (void)in_sizes; (void)n_in; (void)out_size; (void)ws_size;
  const float* x       = (const float*)d_in[0];
  const int*   mask    = (const int*)d_in[1];
  const float* latents = (const float*)d_in[2];
  const float* ln_m_w  = (const float*)d_in[3];
  const float* ln_m_b  = (const float*)d_in[4];
  const float* ln_l_w  = (const float*)d_in[5];
  const float* ln_l_b  = (const float*)d_in[6];
  const float* Wq      = (const float*)d_in[7];
  const float* Wkv     = (const float*)d_in[8];
  const float* Wo      = (const float*)d_in[9];
  const float* ff_ln_w = (const float*)d_in[10];
  const float* ff_ln_b = (const float*)d_in[11];
  const float* W1      = (const float*)d_in[12];
  const float* W2      = (const float*)d_in[13];
  const float* norm_w  = (const float*)d_in[14];
  const float* norm_b  = (const float*)d_in[15];
  float* out = (float*)d_out;

  char* ws = (char*)d_ws;
  size_t off = 0;
  auto alloc = [&](size_t bytes) -> void* {
    void* p = ws + off; off += (bytes + 255) & ~(size_t)255; return p;
  };
  u16* xhat  = (u16*)alloc((size_t)32768 * 1024 * 2);
  u16* kvx   = (u16*)alloc((size_t)32768 * 1024 * 2);
  u16* kvl   = (u16*)alloc((size_t)1024 * 1024 * 2);
  float* lat = (float*)alloc((size_t)1024 * 1024 * 4);
  u16* lnl   = (u16*)alloc((size_t)1024 * 1024 * 2);
  u16* latn  = (u16*)alloc((size_t)1024 * 1024 * 2);
  u16* qb    = (u16*)alloc((size_t)1024 * 512 * 2);
  u16* aout  = (u16*)alloc((size_t)1024 * 512 * 2);
  u16* hf    = (u16*)alloc((size_t)1024 * 4096 * 2);
  u16* WqT   = (u16*)alloc((size_t)512 * 1024 * 2);
  u16* WkvTp = (u16*)alloc((size_t)1024 * 1024 * 2);
  u16* WkvTf = (u16*)alloc((size_t)1024 * 1024 * 2);
  u16* WoT   = (u16*)alloc((size_t)1024 * 512 * 2);
  u16* W1T   = (u16*)alloc((size_t)4096 * 1024 * 2);
  u16* W2T   = (u16*)alloc((size_t)1024 * 4096 * 2);
  float* biaskv = (float*)alloc(1024 * 4);

  // once: normalized x (no affine), lat init
  ln_rows_k<false, false><<<32768, 256, 0, stream>>>(x, nullptr, nullptr, xhat);
  lat_init_k<<<1024, 256, 0, stream>>>(latents, lat);

  for (int i = 0; i < DEPTHC; i++) {
    transp_k<<<dim3(512/32, 1024/32), dim3(32,8), 0, stream>>>(Wq + (size_t)i*1024*512, WqT, nullptr, nullptr, 1024, 512);
    transp_k<<<dim3(1024/32, 1024/32), dim3(32,8), 0, stream>>>(Wkv + (size_t)i*1024*1024, WkvTp, WkvTf, ln_m_w + i*1024, 1024, 1024);
    transp_k<<<dim3(1024/32, 512/32), dim3(32,8), 0, stream>>>(Wo + (size_t)i*512*1024, WoT, nullptr, nullptr, 512, 1024);
    transp_k<<<dim3(4096/32, 1024/32), dim3(32,8), 0, stream>>>(W1 + (size_t)i*1024*4096, W1T, nullptr, nullptr, 1024, 4096);
    transp_k<<<dim3(1024/32, 4096/32), dim3(32,8), 0, stream>>>(W2 + (size_t)i*4096*1024, W2T, nullptr, nullptr, 4096, 1024);
    biascol_k<<<4, 256, 0, stream>>>(ln_m_b + i*1024, Wkv + (size_t)i*1024*1024, biaskv, 1024, 1024);

    ln_rows_k<false, true><<<1024, 256, 0, stream>>>(lat, ln_l_w + i*1024, ln_l_b + i*1024, lnl);
    gemm_k<0><<<dim3(4, 8), 256, 0, stream>>>(lnl, WqT, qb, nullptr, nullptr, 1024, 512, 1024);
    gemm_k<0><<<dim3(8, 8), 256, 0, stream>>>(lnl, WkvTp, kvl, nullptr, nullptr, 1024, 1024, 1024);
    gemm_k<1><<<dim3(8, 256), 256, 0, stream>>>(xhat, WkvTf, kvx, biaskv, nullptr, 32768, 1024, 1024);
    attn_k<<<128, 256, 0, stream>>>(qb, kvx, kvl, mask, aout);
    gemm_k<3><<<dim3(8, 8), 256, 0, stream>>>(aout, WoT, lat, nullptr, lat, 1024, 1024, 512);
    ln_rows_k<false, true><<<1024, 256, 0, stream>>>(lat, ff_ln_w + i*1024, ff_ln_b + i*1024, latn);
    gemm_k<2><<<dim3(32, 8), 256, 0, stream>>>(latn, W1T, hf, nullptr, nullptr, 1024, 4096, 1024);
    gemm_k<3><<<dim3(8, 8), 256, 0, stream>>>(hf, W2T, lat, nullptr, lat, 1024, 1024, 4096);
  }
  ln_rows_k<true, true><<<1024, 256, 0, stream>>>(lat, norm_w, norm_b, out);
}

// Round 2
// 2220.126 us; speedup vs baseline: 1.3129x; 1.3129x over previous
//
#include <hip/hip_runtime.h>

typedef unsigned short u16;
typedef unsigned int u32;
typedef __attribute__((ext_vector_type(8))) short short8;
typedef __attribute__((ext_vector_type(4))) float f4;

#define DEV static __device__ __forceinline__

constexpr int BB = 16, NN = 2048, DD = 1024, HH = 8, DHD = 64, II = 512, LL = 64, DEPTHC = 6, FFC = 4096;

DEV u16 f2bf(float f) {
  union { float f; u32 u; } v; v.f = f;
  u32 r = v.u + 0x7FFFu + ((v.u >> 16) & 1u);
  return (u16)(r >> 16);
}

typedef const u32 __attribute__((address_space(1)))* gas_p;
typedef u32 __attribute__((address_space(3)))* las_p;
DEV void gl_lds16(const void* g, void* l) {
  __builtin_amdgcn_global_load_lds((gas_p)g, (las_p)l, 16, 0, 0);
}

// ---------------- LayerNorm over rows of 1024 ----------------
template<bool OUTF32, bool AFFINE>
__global__ __launch_bounds__(256) void ln_rows_k(const float* __restrict__ in,
    const float* __restrict__ w, const float* __restrict__ bias, void* __restrict__ out) {
  int row = blockIdx.x;
  int tid = threadIdx.x;
  const float4* rp = (const float4*)(in + (size_t)row * DD);
  float4 x = rp[tid];
  float s = x.x + x.y + x.z + x.w;
  float s2 = x.x*x.x + x.y*x.y + x.z*x.z + x.w*x.w;
  #pragma unroll
  for (int off = 32; off >= 1; off >>= 1) {
    s  += __shfl_xor(s, off, 64);
    s2 += __shfl_xor(s2, off, 64);
  }
  __shared__ float red[8];
  int wv = tid >> 6;
  if ((tid & 63) == 0) { red[wv] = s; red[4 + wv] = s2; }
  __syncthreads();
  s  = red[0] + red[1] + red[2] + red[3];
  s2 = red[4] + red[5] + red[6] + red[7];
  float mu = s * (1.f / DD);
  float var = s2 * (1.f / DD) - mu * mu;
  float rstd = rsqrtf(var + 1e-5f);
  float y[4] = {x.x, x.y, x.z, x.w};
  int col = tid * 4;
  #pragma unroll
  for (int j = 0; j < 4; j++) {
    float v = (y[j] - mu) * rstd;
    if (AFFINE) v = v * w[col + j] + bias[col + j];
    y[j] = v;
  }
  if (OUTF32) {
    float4 o = {y[0], y[1], y[2], y[3]};
    ((float4*)out)[(size_t)row * (DD/4) + tid] = o;
  } else {
    ushort4 o = make_ushort4(f2bf(y[0]), f2bf(y[1]), f2bf(y[2]), f2bf(y[3]));
    ((ushort4*)out)[(size_t)row * (DD/4) + tid] = o;
  }
}

// ---------------- lat init: broadcast latents over batch ----------------
__global__ __launch_bounds__(256) void lat_init_k(const float* __restrict__ latents, float* __restrict__ lat) {
  int idx = blockIdx.x * 256 + threadIdx.x;
  ((float4*)lat)[idx] = ((const float4*)latents)[idx & (LL * DD / 4 - 1)];
}

// ---------------- transpose fp32 [R][C] -> bf16 [C][R]; optional scaled copy ----------------
__global__ void transp_k(const float* __restrict__ in, u16* __restrict__ outp,
                         u16* __restrict__ outs, const float* __restrict__ scale, int R, int C) {
  __shared__ float t[32][33];
  int c0 = blockIdx.x * 32, r0 = blockIdx.y * 32;
  int tx = threadIdx.x, ty = threadIdx.y; // 32 x 8
  #pragma unroll
  for (int j = 0; j < 4; j++)
    t[ty + j*8][tx] = in[(size_t)(r0 + ty + j*8) * C + c0 + tx];
  __syncthreads();
  float sc = scale ? scale[r0 + tx] : 1.f;
  #pragma unroll
  for (int j = 0; j < 4; j++) {
    float v = t[tx][ty + j*8];
    size_t o = (size_t)(c0 + ty + j*8) * R + r0 + tx;
    if (outp) outp[o] = f2bf(v);
    if (outs) outs[o] = f2bf(v * sc);
  }
}

// ---------------- zero small buffer ----------------
__global__ void zero_k(float* __restrict__ p, int n) {
  int i = blockIdx.x * 256 + threadIdx.x;
  if (i < n) p[i] = 0.f;
}

// ---------------- bias row: out[j] += sum over 16-row chunk of b[d]*W[d][j] ----------------
// grid: dim3(Ncols/256, Drows/16)
__global__ __launch_bounds__(256) void biascol_k(const float* __restrict__ bvec,
    const float* __restrict__ W, float* __restrict__ out, int Ncols) {
  int col = blockIdx.x * 256 + threadIdx.x;
  int d0 = blockIdx.y * 16;
  float a = 0.f;
  #pragma unroll
  for (int d = 0; d < 16; d++) a += bvec[d0 + d] * W[(size_t)(d0 + d) * Ncols + col];
  atomicAdd(&out[col], a);
}

// ---------------- GEMM 128x128: C[M,N] = A[M,K](bf16) @ Bm[N,K](bf16)^T ----------------
// EPI: 0 = bf16 out, 1 = bf16 + bias[col], 2 = bf16 gelu(exact), 3 = f32 out + resid
// SWZ: linear grid of 2048 blocks (M=32768, N=1024), XCD-swizzled so the 8
//      N-blocks sharing an A-tile land on one XCD (ids congruent mod 8).
template<int EPI, bool SWZ>
__global__ __launch_bounds__(256) void gemm_k(const u16* __restrict__ A, const u16* __restrict__ Bm,
    void* __restrict__ C, const float* __restrict__ bias, const float* __restrict__ resid,
    int M, int N, int K) {
  __shared__ __align__(16) u16 As[128 * 32];
  __shared__ __align__(16) u16 Bs[128 * 32];
  int tid = threadIdx.x;
  int wv = tid >> 6, lane = tid & 63;
  int m0, n0;
  if (SWZ) {
    int id = blockIdx.x;
    int x = id & 7, t = id >> 3;
    m0 = (x * 32 + (t >> 3)) * 128;   // XCD x owns M-tiles [32x, 32x+32)
    n0 = (t & 7) * 128;               // consecutive ids on one XCD sweep N
  } else {
    m0 = blockIdx.y * 128; n0 = blockIdx.x * 128;
  }
  int srow = wv * 16 + (lane >> 2);
  int scol = (lane & 3) * 8;
  const u16* gA0 = A + (size_t)(m0 + srow) * K + scol;
  const u16* gA1 = A + (size_t)(m0 + 64 + srow) * K + scol;
  const u16* gB0 = Bm + (size_t)(n0 + srow) * K + scol;
  const u16* gB1 = Bm + (size_t)(n0 + 64 + srow) * K + scol;
  u16* lA0 = &As[srow * 32 + scol];
  u16* lA1 = &As[(64 + srow) * 32 + scol];
  u16* lB0 = &Bs[srow * 32 + scol];
  u16* lB1 = &Bs[(64 + srow) * 32 + scol];
  int wm = (wv & 1) * 64, wn = (wv >> 1) * 64;
  int fr = lane & 15, fq = (lane >> 4) * 8;
  f4 acc[4][4];
  #pragma unroll
  for (int mi = 0; mi < 4; mi++)
    #pragma unroll
    for (int ni = 0; ni < 4; ni++) acc[mi][ni] = f4{0.f, 0.f, 0.f, 0.f};

  for (int k0 = 0; k0 < K; k0 += 32) {
    gl_lds16(gA0 + k0, lA0);
    gl_lds16(gA1 + k0, lA1);
    gl_lds16(gB0 + k0, lB0);
    gl_lds16(gB1 + k0, lB1);
    __syncthreads();
    short8 af[4], bfr[4];
    #pragma unroll
    for (int mi = 0; mi < 4; mi++)
      af[mi] = *(const short8*)&As[(wm + mi*16 + fr) * 32 + fq];
    #pragma unroll
    for (int ni = 0; ni < 4; ni++)
      bfr[ni] = *(const short8*)&Bs[(wn + ni*16 + fr) * 32 + fq];
    #pragma unroll
    for (int mi = 0; mi < 4; mi++)
      #pragma unroll
      for (int ni = 0; ni < 4; ni++)
        acc[mi][ni] = __builtin_amdgcn_mfma_f32_16x16x32_bf16(af[mi], bfr[ni], acc[mi][ni], 0, 0, 0);
    __syncthreads();
  }
  int er = (lane >> 4) * 4;
  int ec = lane & 15;
  #pragma unroll
  for (int mi = 0; mi < 4; mi++) {
    #pragma unroll
    for (int ni = 0; ni < 4; ni++) {
      int col = n0 + wn + ni*16 + ec;
      #pragma unroll
      for (int r = 0; r < 4; r++) {
        int row = m0 + wm + mi*16 + er + r;
        float v = acc[mi][ni][r];
        if (EPI == 1) v += bias[col];
        if (EPI == 2) v = 0.5f * v * (1.f + erff(v * 0.70710678118654752f));
        size_t off = (size_t)row * N + col;
        if (EPI == 3) ((float*)C)[off] = v + resid[off];
        else          ((u16*)C)[off] = f2bf(v);
      }
    }
  }
}

// ---------------- GEMM 64x64 tile (for small-M latent-side ops: 4x block count) ----------------
template<int EPI>
__global__ __launch_bounds__(256) void gemm64_k(const u16* __restrict__ A, const u16* __restrict__ Bm,
    void* __restrict__ C, const float* __restrict__ bias, const float* __restrict__ resid,
    int M, int N, int K) {
  __shared__ __align__(16) u16 As[64 * 32];
  __shared__ __align__(16) u16 Bs[64 * 32];
  int tid = threadIdx.x;
  int wv = tid >> 6, lane = tid & 63;
  int m0 = blockIdx.y * 64, n0 = blockIdx.x * 64;
  int srow = tid >> 2;            // 0..63
  int scol = (tid & 3) * 8;
  const u16* gA = A + (size_t)(m0 + srow) * K + scol;
  const u16* gB = Bm + (size_t)(n0 + srow) * K + scol;
  u16* lA = &As[srow * 32 + scol];
  u16* lB = &Bs[srow * 32 + scol];
  int wm = (wv & 1) * 32, wn = (wv >> 1) * 32;
  int fr = lane & 15, fq = (lane >> 4) * 8;
  f4 acc[2][2];
  #pragma unroll
  for (int mi = 0; mi < 2; mi++)
    #pragma unroll
    for (int ni = 0; ni < 2; ni++) acc[mi][ni] = f4{0.f, 0.f, 0.f, 0.f};

  for (int k0 = 0; k0 < K; k0 += 32) {
    gl_lds16(gA + k0, lA);
    gl_lds16(gB + k0, lB);
    __syncthreads();
    short8 af[2], bfr[2];
    #pragma unroll
    for (int mi = 0; mi < 2; mi++)
      af[mi] = *(const short8*)&As[(wm + mi*16 + fr) * 32 + fq];
    #pragma unroll
    for (int ni = 0; ni < 2; ni++)
      bfr[ni] = *(const short8*)&Bs[(wn + ni*16 + fr) * 32 + fq];
    #pragma unroll
    for (int mi = 0; mi < 2; mi++)
      #pragma unroll
      for (int ni = 0; ni < 2; ni++)
        acc[mi][ni] = __builtin_amdgcn_mfma_f32_16x16x32_bf16(af[mi], bfr[ni], acc[mi][ni], 0, 0, 0);
    __syncthreads();
  }
  int er = (lane >> 4) * 4;
  int ec = lane & 15;
  #pragma unroll
  for (int mi = 0; mi < 2; mi++) {
    #pragma unroll
    for (int ni = 0; ni < 2; ni++) {
      int col = n0 + wn + ni*16 + ec;
      #pragma unroll
      for (int r = 0; r < 4; r++) {
        int row = m0 + wm + mi*16 + er + r;
        float v = acc[mi][ni][r];
        if (EPI == 1) v += bias[col];
        if (EPI == 2) v = 0.5f * v * (1.f + erff(v * 0.70710678118654752f));
        size_t off = (size_t)row * N + col;
        if (EPI == 3) ((float*)C)[off] = v + resid[off];
        else          ((u16*)C)[off] = f2bf(v);
      }
    }
  }
}

// ---------------- flash attention: one block per (b,h), 33 key tiles of 64 ----------------
__global__ __launch_bounds__(256) void attn_k(const u16* __restrict__ q,
    const u16* __restrict__ kv_x, const u16* __restrict__ kv_lat,
    const int* __restrict__ mask, u16* __restrict__ out) {
  int b = blockIdx.x >> 3;
  int h = blockIdx.x & 7;
  int tid = threadIdx.x;
  int wv = tid >> 6, lane = tid & 63;
  int fr = lane & 15, fq8 = (lane >> 4) * 8;

  __shared__ __align__(16) u16 ks[64 * 88];     // k tile [key][d], pad->88
  __shared__ __align__(16) u16 vs[64 * 88];     // v tile transposed [d][key]
  __shared__ __align__(16) u16 ps[4][16 * 88];  // per-wave P round-trip
  __shared__ float smask[64];

  const u16* qp = q + (size_t)(b * LL + wv * 16 + fr) * II + h * DHD;
  short8 aq0 = *(const short8*)(qp + fq8);
  short8 aq1 = *(const short8*)(qp + 32 + fq8);

  float m_i[4], l_i[4];
  f4 o[4];
  #pragma unroll
  for (int r = 0; r < 4; r++) { m_i[r] = -1e30f; l_i[r] = 0.f; }
  #pragma unroll
  for (int dt = 0; dt < 4; dt++) o[dt] = f4{0.f, 0.f, 0.f, 0.f};

  const float scale = 0.125f; // DH^-0.5

  for (int t = 0; t < 33; t++) {
    __syncthreads();
    const u16* src = (t < 32) ? (kv_x + ((size_t)(b * NN + t * 64)) * 1024 + h * DHD)
                              : (kv_lat + ((size_t)(b * LL)) * 1024 + h * DHD);
    #pragma unroll
    for (int it = 0; it < 2; it++) {
      int cid = it * 256 + tid;       // 512 chunks of 8 elems over 64x64
      int kr = cid >> 3, c8 = (cid & 7) * 8;
      int4 kvv = *(const int4*)(src + (size_t)kr * 1024 + c8);
      *(int4*)&ks[kr * 88 + c8] = kvv;
      int4 vvv = *(const int4*)(src + II + (size_t)kr * 1024 + c8);
      const u16* ve = (const u16*)&vvv;
      #pragma unroll
      for (int j = 0; j < 8; j++) vs[(c8 + j) * 88 + kr] = ve[j];
    }
    if (tid < 64)
      smask[tid] = (t < 32 && mask[b * NN + t * 64 + tid] != 0) ? -1e30f : 0.f;
    __syncthreads();

    // sim = q @ k^T for this wave's 16 q rows x 64 keys
    f4 sim[4];
    #pragma unroll
    for (int ct = 0; ct < 4; ct++) {
      short8 b0 = *(const short8*)&ks[(ct*16 + fr) * 88 + fq8];
      short8 b1 = *(const short8*)&ks[(ct*16 + fr) * 88 + 32 + fq8];
      f4 s = f4{0.f, 0.f, 0.f, 0.f};
      s = __builtin_amdgcn_mfma_f32_16x16x32_bf16(aq0, b0, s, 0, 0, 0);
      s = __builtin_amdgcn_mfma_f32_16x16x32_bf16(aq1, b1, s, 0, 0, 0);
      float mk = smask[ct*16 + fr];
      #pragma unroll
      for (int r = 0; r < 4; r++) s[r] = s[r] * scale + mk;
      sim[ct] = s;
    }
    // online softmax (rows live in quads; 16 lanes/quad hold 16 cols)
    float mnew[4], alpha[4], p[4][4];
    #pragma unroll
    for (int r = 0; r < 4; r++) {
      float mx = fmaxf(fmaxf(sim[0][r], sim[1][r]), fmaxf(sim[2][r], sim[3][r]));
      #pragma unroll
      for (int off = 8; off >= 1; off >>= 1) mx = fmaxf(mx, __shfl_xor(mx, off, 16));
      mnew[r] = fmaxf(m_i[r], mx);
      alpha[r] = __expf(m_i[r] - mnew[r]);
      m_i[r] = mnew[r];
      float ssum = 0.f;
      #pragma unroll
      for (int ct = 0; ct < 4; ct++) { float e = __expf(sim[ct][r] - mnew[r]); p[ct][r] = e; ssum += e; }
      #pragma unroll
      for (int off = 8; off >= 1; off >>= 1) ssum += __shfl_xor(ssum, off, 16);
      l_i[r] = l_i[r] * alpha[r] + ssum;
    }
    // P (C layout) -> LDS -> A layout
    #pragma unroll
    for (int ct = 0; ct < 4; ct++)
      #pragma unroll
      for (int r = 0; r < 4; r++)
        ps[wv][((lane>>4)*4 + r) * 88 + ct*16 + fr] = f2bf(p[ct][r]);
    #pragma unroll
    for (int dt = 0; dt < 4; dt++)
      #pragma unroll
      for (int r = 0; r < 4; r++) o[dt][r] *= alpha[r];
    short8 pa0 = *(const short8*)&ps[wv][fr * 88 + fq8];
    short8 pa1 = *(const short8*)&ps[wv][fr * 88 + 32 + fq8];
    #pragma unroll
    for (int dt = 0; dt < 4; dt++) {
      short8 bv0 = *(const short8*)&vs[(dt*16 + fr) * 88 + fq8];
      short8 bv1 = *(const short8*)&vs[(dt*16 + fr) * 88 + 32 + fq8];
      o[dt] = __builtin_amdgcn_mfma_f32_16x16x32_bf16(pa0, bv0, o[dt], 0, 0, 0);
      o[dt] = __builtin_amdgcn_mfma_f32_16x16x32_bf16(pa1, bv1, o[dt], 0, 0, 0);
    }
  }
  #pragma unroll
  for (int dt = 0; dt < 4; dt++)
    #pragma unroll
    for (int r = 0; r < 4; r++) {
      int row = b * LL + wv * 16 + (lane>>4)*4 + r;
      int col = h * DHD + dt*16 + fr;
      out[(size_t)row * II + col] = f2bf(o[dt][r] / l_i[r]);
    }
}

extern "C" void kernel_launch(void* const* d_in, const int* in_sizes, int n_in,
                              void* d_out, int out_size, void* d_ws, size_t ws_size,
                              hipStream_t stream) {
  (void)in_sizes; (void)n_in; (void)out_size; (void)ws_size;
  const float* x       = (const float*)d_in[0];
  const int*   mask    = (const int*)d_in[1];
  const float* latents = (const float*)d_in[2];
  const float* ln_m_w  = (const float*)d_in[3];
  const float* ln_m_b  = (const float*)d_in[4];
  const float* ln_l_w  = (const float*)d_in[5];
  const float* ln_l_b  = (const float*)d_in[6];
  const float* Wq      = (const float*)d_in[7];
  const float* Wkv     = (const float*)d_in[8];
  const float* Wo      = (const float*)d_in[9];
  const float* ff_ln_w = (const float*)d_in[10];
  const float* ff_ln_b = (const float*)d_in[11];
  const float* W1      = (const float*)d_in[12];
  const float* W2      = (const float*)d_in[13];
  const float* norm_w  = (const float*)d_in[14];
  const float* norm_b  = (const float*)d_in[15];
  float* out = (float*)d_out;

  char* ws = (char*)d_ws;
  size_t off = 0;
  auto alloc = [&](size_t bytes) -> void* {
    void* p = ws + off; off += (bytes + 255) & ~(size_t)255; return p;
  };
  u16* xhat  = (u16*)alloc((size_t)32768 * 1024 * 2);
  u16* kvx   = (u16*)alloc((size_t)32768 * 1024 * 2);
  u16* kvl   = (u16*)alloc((size_t)1024 * 1024 * 2);
  float* lat = (float*)alloc((size_t)1024 * 1024 * 4);
  u16* lnl   = (u16*)alloc((size_t)1024 * 1024 * 2);
  u16* latn  = (u16*)alloc((size_t)1024 * 1024 * 2);
  u16* qb    = (u16*)alloc((size_t)1024 * 512 * 2);
  u16* aout  = (u16*)alloc((size_t)1024 * 512 * 2);
  u16* hf    = (u16*)alloc((size_t)1024 * 4096 * 2);
  u16* WqT   = (u16*)alloc((size_t)512 * 1024 * 2);
  u16* WkvTp = (u16*)alloc((size_t)1024 * 1024 * 2);
  u16* WkvTf = (u16*)alloc((size_t)1024 * 1024 * 2);
  u16* WoT   = (u16*)alloc((size_t)1024 * 512 * 2);
  u16* W1T   = (u16*)alloc((size_t)4096 * 1024 * 2);
  u16* W2T   = (u16*)alloc((size_t)1024 * 4096 * 2);
  float* biaskv = (float*)alloc(1024 * 4);

  // once: normalized x (no affine), lat init
  ln_rows_k<false, false><<<32768, 256, 0, stream>>>(x, nullptr, nullptr, xhat);
  lat_init_k<<<1024, 256, 0, stream>>>(latents, lat);

  for (int i = 0; i < DEPTHC; i++) {
    transp_k<<<dim3(512/32, 1024/32), dim3(32,8), 0, stream>>>(Wq + (size_t)i*1024*512, WqT, nullptr, nullptr, 1024, 512);
    transp_k<<<dim3(1024/32, 1024/32), dim3(32,8), 0, stream>>>(Wkv + (size_t)i*1024*1024, WkvTp, WkvTf, ln_m_w + i*1024, 1024, 1024);
    transp_k<<<dim3(1024/32, 512/32), dim3(32,8), 0, stream>>>(Wo + (size_t)i*512*1024, WoT, nullptr, nullptr, 512, 1024);
    transp_k<<<dim3(4096/32, 1024/32), dim3(32,8), 0, stream>>>(W1 + (size_t)i*1024*4096, W1T, nullptr, nullptr, 1024, 4096);
    transp_k<<<dim3(1024/32, 4096/32), dim3(32,8), 0, stream>>>(W2 + (size_t)i*4096*1024, W2T, nullptr, nullptr, 4096, 1024);
    zero_k<<<4, 256, 0, stream>>>(biaskv, 1024);
    biascol_k<<<dim3(4, 64), 256, 0, stream>>>(ln_m_b + i*1024, Wkv + (size_t)i*1024*1024, biaskv, 1024);

    ln_rows_k<false, true><<<1024, 256, 0, stream>>>(lat, ln_l_w + i*1024, ln_l_b + i*1024, lnl);
    gemm64_k<0><<<dim3(8, 16), 256, 0, stream>>>(lnl, WqT, qb, nullptr, nullptr, 1024, 512, 1024);
    gemm64_k<0><<<dim3(16, 16), 256, 0, stream>>>(lnl, WkvTp, kvl, nullptr, nullptr, 1024, 1024, 1024);
    gemm_k<1, true><<<dim3(2048), 256, 0, stream>>>(xhat, WkvTf, kvx, biaskv, nullptr, 32768, 1024, 1024);
    attn_k<<<128, 256, 0, stream>>>(qb, kvx, kvl, mask, aout);
    gemm64_k<3><<<dim3(16, 16), 256, 0, stream>>>(aout, WoT, lat, nullptr, lat, 1024, 1024, 512);
    ln_rows_k<false, true><<<1024, 256, 0, stream>>>(lat, ff_ln_w + i*1024, ff_ln_b + i*1024, latn);
    gemm_k<2, false><<<dim3(32, 8), 256, 0, stream>>>(latn, W1T, hf, nullptr, nullptr, 1024, 4096, 1024);
    gemm64_k<3><<<dim3(16, 16), 256, 0, stream>>>(hf, W2T, lat, nullptr, lat, 1024, 1024, 4096);
  }
  ln_rows_k<true, true><<<1024, 256, 0, stream>>>(lat, norm_w, norm_b, out);
}

// Round 3
// 1599.374 us; speedup vs baseline: 1.8224x; 1.3881x over previous
//
#include <hip/hip_runtime.h>

typedef unsigned short u16;
typedef unsigned int u32;
typedef __attribute__((ext_vector_type(8))) short short8;
typedef __attribute__((ext_vector_type(4))) float f4;

#define DEV static __device__ __forceinline__

constexpr int BB = 16, NN = 2048, DD = 1024, HH = 8, DHD = 64, II = 512, LL = 64, DEPTHC = 6, FFC = 4096;

DEV u16 f2bf(float f) {
  union { float f; u32 u; } v; v.f = f;
  u32 r = v.u + 0x7FFFu + ((v.u >> 16) & 1u);
  return (u16)(r >> 16);
}

typedef const u32 __attribute__((address_space(1)))* gas_p;
typedef u32 __attribute__((address_space(3)))* las_p;
DEV void gl_lds16(const void* g, void* l) {
  __builtin_amdgcn_global_load_lds((gas_p)g, (las_p)l, 16, 0, 0);
}

// ---------------- mask prefix-scan: per batch, list of unmasked (mask==0) indices ----------------
__global__ __launch_bounds__(256) void maskscan_k(const int* __restrict__ mask,
    int* __restrict__ idx, int* __restrict__ cnt) {
  int b = blockIdx.x, tid = threadIdx.x;
  int lane = tid & 63, wv = tid >> 6;
  const int* mrow = mask + (size_t)b * NN;
  int base = tid * 8;
  int keep[8]; int local = 0;
  #pragma unroll
  for (int j = 0; j < 8; j++) { keep[j] = (mrow[base + j] == 0); local += keep[j]; }
  int incl = local;
  #pragma unroll
  for (int off = 1; off < 64; off <<= 1) {
    int v = __shfl_up(incl, off, 64);
    if (lane >= off) incl += v;
  }
  __shared__ int wsum[4];
  if (lane == 63) wsum[wv] = incl;
  __syncthreads();
  int wbase = 0;
  for (int w = 0; w < wv; w++) wbase += wsum[w];
  int pos = wbase + incl - local;
  #pragma unroll
  for (int j = 0; j < 8; j++) if (keep[j]) idx[(size_t)b * NN + pos++] = base + j;
  if (tid == 255) cnt[b] = wbase + incl;
}

// ---------------- fused LN + gather: xcomp[b][j] = LN(x[b][idx[b][j]]); pad rows zeroed ----------------
__global__ __launch_bounds__(256) void ln_gather_k(const float* __restrict__ x,
    const int* __restrict__ idx, const int* __restrict__ cnt, u16* __restrict__ xcomp) {
  int b = blockIdx.y, j = blockIdx.x, tid = threadIdx.x;
  int c = cnt[b];
  if (j >= ((c + 127) & ~127)) return;
  ushort4* orow = (ushort4*)(xcomp + ((size_t)b * NN + j) * DD);
  if (j >= c) { orow[tid] = make_ushort4(0, 0, 0, 0); return; }
  int src = idx[(size_t)b * NN + j];
  const float4* rp = (const float4*)(x + ((size_t)b * NN + src) * DD);
  float4 v = rp[tid];
  float s = v.x + v.y + v.z + v.w;
  float s2 = v.x*v.x + v.y*v.y + v.z*v.z + v.w*v.w;
  #pragma unroll
  for (int off = 32; off >= 1; off >>= 1) {
    s  += __shfl_xor(s, off, 64);
    s2 += __shfl_xor(s2, off, 64);
  }
  __shared__ float red[8];
  int wv = tid >> 6;
  if ((tid & 63) == 0) { red[wv] = s; red[4 + wv] = s2; }
  __syncthreads();
  s  = red[0] + red[1] + red[2] + red[3];
  s2 = red[4] + red[5] + red[6] + red[7];
  float mu = s * (1.f / DD);
  float var = s2 * (1.f / DD) - mu * mu;
  float rstd = rsqrtf(var + 1e-5f);
  orow[tid] = make_ushort4(f2bf((v.x - mu) * rstd), f2bf((v.y - mu) * rstd),
                           f2bf((v.z - mu) * rstd), f2bf((v.w - mu) * rstd));
}

// ---------------- LayerNorm over rows of 1024 (latent path) ----------------
template<bool OUTF32, bool AFFINE>
__global__ __launch_bounds__(256) void ln_rows_k(const float* __restrict__ in,
    const float* __restrict__ w, const float* __restrict__ bias, void* __restrict__ out) {
  int row = blockIdx.x;
  int tid = threadIdx.x;
  const float4* rp = (const float4*)(in + (size_t)row * DD);
  float4 x = rp[tid];
  float s = x.x + x.y + x.z + x.w;
  float s2 = x.x*x.x + x.y*x.y + x.z*x.z + x.w*x.w;
  #pragma unroll
  for (int off = 32; off >= 1; off >>= 1) {
    s  += __shfl_xor(s, off, 64);
    s2 += __shfl_xor(s2, off, 64);
  }
  __shared__ float red[8];
  int wv = tid >> 6;
  if ((tid & 63) == 0) { red[wv] = s; red[4 + wv] = s2; }
  __syncthreads();
  s  = red[0] + red[1] + red[2] + red[3];
  s2 = red[4] + red[5] + red[6] + red[7];
  float mu = s * (1.f / DD);
  float var = s2 * (1.f / DD) - mu * mu;
  float rstd = rsqrtf(var + 1e-5f);
  float y[4] = {x.x, x.y, x.z, x.w};
  int col = tid * 4;
  #pragma unroll
  for (int j = 0; j < 4; j++) {
    float v = (y[j] - mu) * rstd;
    if (AFFINE) v = v * w[col + j] + bias[col + j];
    y[j] = v;
  }
  if (OUTF32) {
    float4 o = {y[0], y[1], y[2], y[3]};
    ((float4*)out)[(size_t)row * (DD/4) + tid] = o;
  } else {
    ushort4 o = make_ushort4(f2bf(y[0]), f2bf(y[1]), f2bf(y[2]), f2bf(y[3]));
    ((ushort4*)out)[(size_t)row * (DD/4) + tid] = o;
  }
}

// ---------------- lat init: broadcast latents over batch ----------------
__global__ __launch_bounds__(256) void lat_init_k(const float* __restrict__ latents, float* __restrict__ lat) {
  int idx = blockIdx.x * 256 + threadIdx.x;
  ((float4*)lat)[idx] = ((const float4*)latents)[idx & (LL * DD / 4 - 1)];
}

// ---------------- zero small buffer ----------------
__global__ void zero_k(float* __restrict__ p, int n) {
  int i = blockIdx.x * 256 + threadIdx.x;
  if (i < n) p[i] = 0.f;
}

// ---------------- one launch: all weight transposes for one depth + kv bias GEMV ----------------
// id ranges: [0,512) Wq -> WqkvT rows 0-511 ; [512,1536) Wkv -> WqkvT rows 512-1535 (+ scaled WkvTf + bias)
//            [1536,2048) Wo ; [2048,6144) W1 ; [6144,10240) W2
__global__ void transpall_k(const float* __restrict__ Wq, const float* __restrict__ Wkv,
    const float* __restrict__ Wo, const float* __restrict__ W1, const float* __restrict__ W2,
    const float* __restrict__ lnw, const float* __restrict__ lnb,
    u16* __restrict__ WqkvT, u16* __restrict__ WkvTf, u16* __restrict__ WoT,
    u16* __restrict__ W1T, u16* __restrict__ W2T, float* __restrict__ biaskv) {
  __shared__ float t[32][33];
  __shared__ float bred[8][32];
  int id = blockIdx.x;
  const float* in; u16* o1; int R, C, c0, r0;
  bool iskv = false;
  if (id < 512)       { in = Wq;  R = 1024; C = 512;  int l = id;        c0 = (l % 16) * 32;  r0 = (l / 16) * 32;  o1 = WqkvT; }
  else if (id < 1536) { in = Wkv; R = 1024; C = 1024; int l = id - 512;  c0 = (l % 32) * 32;  r0 = (l / 32) * 32;  o1 = WqkvT + 512 * 1024; iskv = true; }
  else if (id < 2048) { in = Wo;  R = 512;  C = 1024; int l = id - 1536; c0 = (l % 32) * 32;  r0 = (l / 32) * 32;  o1 = WoT; }
  else if (id < 6144) { in = W1;  R = 1024; C = 4096; int l = id - 2048; c0 = (l % 128) * 32; r0 = (l / 128) * 32; o1 = W1T; }
  else                { in = W2;  R = 4096; C = 1024; int l = id - 6144; c0 = (l % 32) * 32;  r0 = (l / 32) * 32;  o1 = W2T; }
  int tx = threadIdx.x, ty = threadIdx.y; // 32 x 8
  #pragma unroll
  for (int j = 0; j < 4; j++)
    t[ty + j*8][tx] = in[(size_t)(r0 + ty + j*8) * C + c0 + tx];
  __syncthreads();
  #pragma unroll
  for (int j = 0; j < 4; j++) {
    float v = t[tx][ty + j*8];
    o1[(size_t)(c0 + ty + j*8) * R + r0 + tx] = f2bf(v);
  }
  if (iskv) {
    float sc = lnw[r0 + tx];
    #pragma unroll
    for (int j = 0; j < 4; j++)
      WkvTf[(size_t)(c0 + ty + j*8) * 1024 + r0 + tx] = f2bf(t[tx][ty + j*8] * sc);
    float partial = 0.f;
    #pragma unroll
    for (int rr = 0; rr < 4; rr++)
      partial += lnb[r0 + ty + rr*8] * t[ty + rr*8][tx];
    bred[ty][tx] = partial;
    __syncthreads();
    if (ty == 0) {
      float sum = 0.f;
      #pragma unroll
      for (int w = 0; w < 8; w++) sum += bred[w][tx];
      atomicAdd(&biaskv[c0 + tx], sum);
    }
  }
}

// ---------------- GEMM 128x128: C[M,N] = A[M,K](bf16) @ Bm[N,K](bf16)^T ----------------
// EPI: 1 = bf16 + bias[col], 2 = bf16 gelu(exact)
// SWZ: linear grid 2048 (M=32768 compacted, N=1024), XCD-swizzled, early-exit past cnt[batch]
template<int EPI, bool SWZ>
__global__ __launch_bounds__(256) void gemm_k(const u16* __restrict__ A, const u16* __restrict__ Bm,
    void* __restrict__ C, const float* __restrict__ bias, const int* __restrict__ cnt,
    int M, int N, int K) {
  __shared__ __align__(16) u16 As[128 * 32];
  __shared__ __align__(16) u16 Bs[128 * 32];
  int tid = threadIdx.x;
  int wv = tid >> 6, lane = tid & 63;
  int m0, n0;
  if (SWZ) {
    int id = blockIdx.x;
    int xg = id & 7, t = id >> 3;
    int mtile = xg * 32 + (t >> 3);   // 0..255, XCD xg owns a contiguous slab
    n0 = (t & 7) * 128;
    int batch = mtile >> 4;
    int ml = (mtile & 15) * 128;
    if (ml >= cnt[batch]) return;     // compacted: whole tile beyond valid rows
    m0 = batch * NN + ml;
  } else {
    m0 = blockIdx.y * 128; n0 = blockIdx.x * 128;
  }
  int srow = wv * 16 + (lane >> 2);
  int scol = (lane & 3) * 8;
  const u16* gA0 = A + (size_t)(m0 + srow) * K + scol;
  const u16* gA1 = A + (size_t)(m0 + 64 + srow) * K + scol;
  const u16* gB0 = Bm + (size_t)(n0 + srow) * K + scol;
  const u16* gB1 = Bm + (size_t)(n0 + 64 + srow) * K + scol;
  u16* lA0 = &As[srow * 32 + scol];
  u16* lA1 = &As[(64 + srow) * 32 + scol];
  u16* lB0 = &Bs[srow * 32 + scol];
  u16* lB1 = &Bs[(64 + srow) * 32 + scol];
  int wm = (wv & 1) * 64, wn = (wv >> 1) * 64;
  int fr = lane & 15, fq = (lane >> 4) * 8;
  f4 acc[4][4];
  #pragma unroll
  for (int mi = 0; mi < 4; mi++)
    #pragma unroll
    for (int ni = 0; ni < 4; ni++) acc[mi][ni] = f4{0.f, 0.f, 0.f, 0.f};

  for (int k0 = 0; k0 < K; k0 += 32) {
    gl_lds16(gA0 + k0, lA0);
    gl_lds16(gA1 + k0, lA1);
    gl_lds16(gB0 + k0, lB0);
    gl_lds16(gB1 + k0, lB1);
    __syncthreads();
    short8 af[4], bfr[4];
    #pragma unroll
    for (int mi = 0; mi < 4; mi++)
      af[mi] = *(const short8*)&As[(wm + mi*16 + fr) * 32 + fq];
    #pragma unroll
    for (int ni = 0; ni < 4; ni++)
      bfr[ni] = *(const short8*)&Bs[(wn + ni*16 + fr) * 32 + fq];
    #pragma unroll
    for (int mi = 0; mi < 4; mi++)
      #pragma unroll
      for (int ni = 0; ni < 4; ni++)
        acc[mi][ni] = __builtin_amdgcn_mfma_f32_16x16x32_bf16(af[mi], bfr[ni], acc[mi][ni], 0, 0, 0);
    __syncthreads();
  }
  int er = (lane >> 4) * 4;
  int ec = lane & 15;
  #pragma unroll
  for (int mi = 0; mi < 4; mi++) {
    #pragma unroll
    for (int ni = 0; ni < 4; ni++) {
      int col = n0 + wn + ni*16 + ec;
      #pragma unroll
      for (int r = 0; r < 4; r++) {
        int row = m0 + wm + mi*16 + er + r;
        float v = acc[mi][ni][r];
        if (EPI == 1) v += bias[col];
        if (EPI == 2) v = 0.5f * v * (1.f + erff(v * 0.70710678118654752f));
        ((u16*)C)[(size_t)row * N + col] = f2bf(v);
      }
    }
  }
}

// ---------------- split-K GEMM 128x128, fp32 atomicAdd epilogue (C pre-holds residual) ----------------
__global__ __launch_bounds__(256) void gemmsk_k(const u16* __restrict__ A, const u16* __restrict__ Bm,
    float* __restrict__ C, int M, int N, int K, int Kc) {
  __shared__ __align__(16) u16 As[128 * 32];
  __shared__ __align__(16) u16 Bs[128 * 32];
  int tid = threadIdx.x;
  int wv = tid >> 6, lane = tid & 63;
  int m0 = blockIdx.y * 128, n0 = blockIdx.x * 128;
  int kb = blockIdx.z * Kc;
  int srow = wv * 16 + (lane >> 2);
  int scol = (lane & 3) * 8;
  const u16* gA0 = A + (size_t)(m0 + srow) * K + kb + scol;
  const u16* gA1 = A + (size_t)(m0 + 64 + srow) * K + kb + scol;
  const u16* gB0 = Bm + (size_t)(n0 + srow) * K + kb + scol;
  const u16* gB1 = Bm + (size_t)(n0 + 64 + srow) * K + kb + scol;
  u16* lA0 = &As[srow * 32 + scol];
  u16* lA1 = &As[(64 + srow) * 32 + scol];
  u16* lB0 = &Bs[srow * 32 + scol];
  u16* lB1 = &Bs[(64 + srow) * 32 + scol];
  int wm = (wv & 1) * 64, wn = (wv >> 1) * 64;
  int fr = lane & 15, fq = (lane >> 4) * 8;
  f4 acc[4][4];
  #pragma unroll
  for (int mi = 0; mi < 4; mi++)
    #pragma unroll
    for (int ni = 0; ni < 4; ni++) acc[mi][ni] = f4{0.f, 0.f, 0.f, 0.f};

  for (int k0 = 0; k0 < Kc; k0 += 32) {
    gl_lds16(gA0 + k0, lA0);
    gl_lds16(gA1 + k0, lA1);
    gl_lds16(gB0 + k0, lB0);
    gl_lds16(gB1 + k0, lB1);
    __syncthreads();
    short8 af[4], bfr[4];
    #pragma unroll
    for (int mi = 0; mi < 4; mi++)
      af[mi] = *(const short8*)&As[(wm + mi*16 + fr) * 32 + fq];
    #pragma unroll
    for (int ni = 0; ni < 4; ni++)
      bfr[ni] = *(const short8*)&Bs[(wn + ni*16 + fr) * 32 + fq];
    #pragma unroll
    for (int mi = 0; mi < 4; mi++)
      #pragma unroll
      for (int ni = 0; ni < 4; ni++)
        acc[mi][ni] = __builtin_amdgcn_mfma_f32_16x16x32_bf16(af[mi], bfr[ni], acc[mi][ni], 0, 0, 0);
    __syncthreads();
  }
  int er = (lane >> 4) * 4;
  int ec = lane & 15;
  #pragma unroll
  for (int mi = 0; mi < 4; mi++)
    #pragma unroll
    for (int ni = 0; ni < 4; ni++) {
      int col = n0 + wn + ni*16 + ec;
      #pragma unroll
      for (int r = 0; r < 4; r++) {
        int row = m0 + wm + mi*16 + er + r;
        atomicAdd(&C[(size_t)row * N + col], acc[mi][ni][r]);
      }
    }
}

// ---------------- GEMM 64x64 tile (latent qkv: M=1024, N=1536) ----------------
__global__ __launch_bounds__(256) void gemm64_k(const u16* __restrict__ A, const u16* __restrict__ Bm,
    u16* __restrict__ C, int M, int N, int K) {
  __shared__ __align__(16) u16 As[64 * 32];
  __shared__ __align__(16) u16 Bs[64 * 32];
  int tid = threadIdx.x;
  int wv = tid >> 6, lane = tid & 63;
  int m0 = blockIdx.y * 64, n0 = blockIdx.x * 64;
  int srow = tid >> 2;
  int scol = (tid & 3) * 8;
  const u16* gA = A + (size_t)(m0 + srow) * K + scol;
  const u16* gB = Bm + (size_t)(n0 + srow) * K + scol;
  u16* lA = &As[srow * 32 + scol];
  u16* lB = &Bs[srow * 32 + scol];
  int wm = (wv & 1) * 32, wn = (wv >> 1) * 32;
  int fr = lane & 15, fq = (lane >> 4) * 8;
  f4 acc[2][2];
  #pragma unroll
  for (int mi = 0; mi < 2; mi++)
    #pragma unroll
    for (int ni = 0; ni < 2; ni++) acc[mi][ni] = f4{0.f, 0.f, 0.f, 0.f};

  for (int k0 = 0; k0 < K; k0 += 32) {
    gl_lds16(gA + k0, lA);
    gl_lds16(gB + k0, lB);
    __syncthreads();
    short8 af[2], bfr[2];
    #pragma unroll
    for (int mi = 0; mi < 2; mi++)
      af[mi] = *(const short8*)&As[(wm + mi*16 + fr) * 32 + fq];
    #pragma unroll
    for (int ni = 0; ni < 2; ni++)
      bfr[ni] = *(const short8*)&Bs[(wn + ni*16 + fr) * 32 + fq];
    #pragma unroll
    for (int mi = 0; mi < 2; mi++)
      #pragma unroll
      for (int ni = 0; ni < 2; ni++)
        acc[mi][ni] = __builtin_amdgcn_mfma_f32_16x16x32_bf16(af[mi], bfr[ni], acc[mi][ni], 0, 0, 0);
    __syncthreads();
  }
  int er = (lane >> 4) * 4;
  int ec = lane & 15;
  #pragma unroll
  for (int mi = 0; mi < 2; mi++)
    #pragma unroll
    for (int ni = 0; ni < 2; ni++) {
      int col = n0 + wn + ni*16 + ec;
      #pragma unroll
      for (int r = 0; r < 4; r++) {
        int row = m0 + wm + mi*16 + er + r;
        C[(size_t)row * N + col] = f2bf(acc[mi][ni][r]);
      }
    }
}

// ---------------- flash attention over compacted keys + latent tile ----------------
// qkv: [1024][1536] = [q(512) | k_lat(512) | v_lat(512)]; kvx: [16*2048][1024] compacted
__global__ __launch_bounds__(256) void attn_k(const u16* __restrict__ qkv,
    const u16* __restrict__ kvx, const int* __restrict__ cnt, u16* __restrict__ out) {
  int b = blockIdx.x >> 3;
  int h = blockIdx.x & 7;
  int tid = threadIdx.x;
  int wv = tid >> 6, lane = tid & 63;
  int fr = lane & 15, fq8 = (lane >> 4) * 8;
  int c = cnt[b];
  int nt = (c + 63) >> 6;   // x-key tiles; tile nt is the latent tile

  __shared__ __align__(16) u16 ks[64 * 88];
  __shared__ __align__(16) u16 vs[64 * 88];
  __shared__ __align__(16) u16 ps[4][16 * 88];
  __shared__ float smask[64];

  const u16* qp = qkv + (size_t)(b * LL + wv * 16 + fr) * 1536 + h * DHD;
  short8 aq0 = *(const short8*)(qp + fq8);
  short8 aq1 = *(const short8*)(qp + 32 + fq8);

  float m_i[4], l_i[4];
  f4 o[4];
  #pragma unroll
  for (int r = 0; r < 4; r++) { m_i[r] = -1e30f; l_i[r] = 0.f; }
  #pragma unroll
  for (int dt = 0; dt < 4; dt++) o[dt] = f4{0.f, 0.f, 0.f, 0.f};

  const float scale = 0.125f;

  for (int t = 0; t <= nt; t++) {
    bool isLat = (t == nt);
    const u16* src;
    int rs;
    if (isLat) { src = qkv + (size_t)(b * LL) * 1536 + 512 + h * DHD; rs = 1536; }
    else       { src = kvx + (size_t)(b * NN + t * 64) * 1024 + h * DHD; rs = 1024; }
    __syncthreads();
    #pragma unroll
    for (int it = 0; it < 2; it++) {
      int cid = it * 256 + tid;
      int kr = cid >> 3, c8 = (cid & 7) * 8;
      int4 kvv = *(const int4*)(src + (size_t)kr * rs + c8);
      *(int4*)&ks[kr * 88 + c8] = kvv;
      int4 vvv = *(const int4*)(src + 512 + (size_t)kr * rs + c8);
      const u16* ve = (const u16*)&vvv;
      #pragma unroll
      for (int j = 0; j < 8; j++) vs[(c8 + j) * 88 + kr] = ve[j];
    }
    if (tid < 64)
      smask[tid] = (isLat || (t * 64 + tid < c)) ? 0.f : -1e30f;
    __syncthreads();

    f4 sim[4];
    #pragma unroll
    for (int ct = 0; ct < 4; ct++) {
      short8 b0 = *(const short8*)&ks[(ct*16 + fr) * 88 + fq8];
      short8 b1 = *(const short8*)&ks[(ct*16 + fr) * 88 + 32 + fq8];
      f4 s = f4{0.f, 0.f, 0.f, 0.f};
      s = __builtin_amdgcn_mfma_f32_16x16x32_bf16(aq0, b0, s, 0, 0, 0);
      s = __builtin_amdgcn_mfma_f32_16x16x32_bf16(aq1, b1, s, 0, 0, 0);
      float mk = smask[ct*16 + fr];
      #pragma unroll
      for (int r = 0; r < 4; r++) s[r] = s[r] * scale + mk;
      sim[ct] = s;
    }
    float mnew[4], alpha[4], p[4][4];
    #pragma unroll
    for (int r = 0; r < 4; r++) {
      float mx = fmaxf(fmaxf(sim[0][r], sim[1][r]), fmaxf(sim[2][r], sim[3][r]));
      #pragma unroll
      for (int off = 8; off >= 1; off >>= 1) mx = fmaxf(mx, __shfl_xor(mx, off, 16));
      mnew[r] = fmaxf(m_i[r], mx);
      alpha[r] = __expf(m_i[r] - mnew[r]);
      m_i[r] = mnew[r];
      float ssum = 0.f;
      #pragma unroll
      for (int ct = 0; ct < 4; ct++) { float e = __expf(sim[ct][r] - mnew[r]); p[ct][r] = e; ssum += e; }
      #pragma unroll
      for (int off = 8; off >= 1; off >>= 1) ssum += __shfl_xor(ssum, off, 16);
      l_i[r] = l_i[r] * alpha[r] + ssum;
    }
    #pragma unroll
    for (int ct = 0; ct < 4; ct++)
      #pragma unroll
      for (int r = 0; r < 4; r++)
        ps[wv][((lane>>4)*4 + r) * 88 + ct*16 + fr] = f2bf(p[ct][r]);
    #pragma unroll
    for (int dt = 0; dt < 4; dt++)
      #pragma unroll
      for (int r = 0; r < 4; r++) o[dt][r] *= alpha[r];
    short8 pa0 = *(const short8*)&ps[wv][fr * 88 + fq8];
    short8 pa1 = *(const short8*)&ps[wv][fr * 88 + 32 + fq8];
    #pragma unroll
    for (int dt = 0; dt < 4; dt++) {
      short8 bv0 = *(const short8*)&vs[(dt*16 + fr) * 88 + fq8];
      short8 bv1 = *(const short8*)&vs[(dt*16 + fr) * 88 + 32 + fq8];
      o[dt] = __builtin_amdgcn_mfma_f32_16x16x32_bf16(pa0, bv0, o[dt], 0, 0, 0);
      o[dt] = __builtin_amdgcn_mfma_f32_16x16x32_bf16(pa1, bv1, o[dt], 0, 0, 0);
    }
  }
  #pragma unroll
  for (int dt = 0; dt < 4; dt++)
    #pragma unroll
    for (int r = 0; r < 4; r++) {
      int row = b * LL + wv * 16 + (lane>>4)*4 + r;
      int col = h * DHD + dt*16 + fr;
      out[(size_t)row * II + col] = f2bf(o[dt][r] / l_i[r]);
    }
}

extern "C" void kernel_launch(void* const* d_in, const int* in_sizes, int n_in,
                              void* d_out, int out_size, void* d_ws, size_t ws_size,
                              hipStream_t stream) {
  (void)in_sizes; (void)n_in; (void)out_size; (void)ws_size;
  const float* x       = (const float*)d_in[0];
  const int*   mask    = (const int*)d_in[1];
  const float* latents = (const float*)d_in[2];
  const float* ln_m_w  = (const float*)d_in[3];
  const float* ln_m_b  = (const float*)d_in[4];
  const float* ln_l_w  = (const float*)d_in[5];
  const float* ln_l_b  = (const float*)d_in[6];
  const float* Wq      = (const float*)d_in[7];
  const float* Wkv     = (const float*)d_in[8];
  const float* Wo      = (const float*)d_in[9];
  const float* ff_ln_w = (const float*)d_in[10];
  const float* ff_ln_b = (const float*)d_in[11];
  const float* W1      = (const float*)d_in[12];
  const float* W2      = (const float*)d_in[13];
  const float* norm_w  = (const float*)d_in[14];
  const float* norm_b  = (const float*)d_in[15];
  float* out = (float*)d_out;

  char* ws = (char*)d_ws;
  size_t off = 0;
  auto alloc = [&](size_t bytes) -> void* {
    void* p = ws + off; off += (bytes + 255) & ~(size_t)255; return p;
  };
  u16* xcomp = (u16*)alloc((size_t)32768 * 1024 * 2);
  u16* kvx   = (u16*)alloc((size_t)32768 * 1024 * 2);
  int* idxb  = (int*)alloc((size_t)32768 * 4);
  int* cnt   = (int*)alloc(64);
  float* lat = (float*)alloc((size_t)1024 * 1024 * 4);
  u16* lnl   = (u16*)alloc((size_t)1024 * 1024 * 2);
  u16* latn  = (u16*)alloc((size_t)1024 * 1024 * 2);
  u16* qkv   = (u16*)alloc((size_t)1024 * 1536 * 2);
  u16* aout  = (u16*)alloc((size_t)1024 * 512 * 2);
  u16* hf    = (u16*)alloc((size_t)1024 * 4096 * 2);
  u16* WqkvT = (u16*)alloc((size_t)1536 * 1024 * 2);
  u16* WkvTf = (u16*)alloc((size_t)1024 * 1024 * 2);
  u16* WoT   = (u16*)alloc((size_t)1024 * 512 * 2);
  u16* W1T   = (u16*)alloc((size_t)4096 * 1024 * 2);
  u16* W2T   = (u16*)alloc((size_t)1024 * 4096 * 2);
  float* biaskv_all = (float*)alloc(6144 * 4);

  // pre-loop: compaction + fused LN gather, lat init, zero bias accumulators
  maskscan_k<<<16, 256, 0, stream>>>(mask, idxb, cnt);
  ln_gather_k<<<dim3(2048, 16), 256, 0, stream>>>(x, idxb, cnt, xcomp);
  lat_init_k<<<1024, 256, 0, stream>>>(latents, lat);
  zero_k<<<24, 256, 0, stream>>>(biaskv_all, 6144);

  for (int i = 0; i < DEPTHC; i++) {
    transpall_k<<<10240, dim3(32, 8), 0, stream>>>(
        Wq + (size_t)i*1024*512, Wkv + (size_t)i*1024*1024, Wo + (size_t)i*512*1024,
        W1 + (size_t)i*1024*4096, W2 + (size_t)i*4096*1024,
        ln_m_w + i*1024, ln_m_b + i*1024,
        WqkvT, WkvTf, WoT, W1T, W2T, biaskv_all + i*1024);
    ln_rows_k<false, true><<<1024, 256, 0, stream>>>(lat, ln_l_w + i*1024, ln_l_b + i*1024, lnl);
    gemm64_k<<<dim3(24, 16), 256, 0, stream>>>(lnl, WqkvT, qkv, 1024, 1536, 1024);
    gemm_k<1, true><<<2048, 256, 0, stream>>>(xcomp, WkvTf, kvx, biaskv_all + i*1024, cnt, 32768, 1024, 1024);
    attn_k<<<128, 256, 0, stream>>>(qkv, kvx, cnt, aout);
    gemmsk_k<<<dim3(8, 8, 4), 256, 0, stream>>>(aout, WoT, lat, 1024, 1024, 512, 128);
    ln_rows_k<false, true><<<1024, 256, 0, stream>>>(lat, ff_ln_w + i*1024, ff_ln_b + i*1024, latn);
    gemm_k<2, false><<<dim3(32, 8), 256, 0, stream>>>(latn, W1T, hf, nullptr, nullptr, 1024, 4096, 1024);
    gemmsk_k<<<dim3(8, 8, 4), 256, 0, stream>>>(hf, W2T, lat, 1024, 1024, 4096, 1024);
  }
  ln_rows_k<true, true><<<1024, 256, 0, stream>>>(lat, norm_w, norm_b, out);
}

// Round 4
// 1497.400 us; speedup vs baseline: 1.9465x; 1.0681x over previous
//
#include <hip/hip_runtime.h>

typedef unsigned short u16;
typedef unsigned int u32;
typedef __attribute__((ext_vector_type(8))) short short8;
typedef __attribute__((ext_vector_type(4))) float f4;

#define DEV static __device__ __forceinline__

constexpr int BB = 16, NN = 2048, DD = 1024, HH = 8, DHD = 64, II = 512, LL = 64, DEPTHC = 6, FFC = 4096;

DEV u16 f2bf(float f) {
  union { float f; u32 u; } v; v.f = f;
  u32 r = v.u + 0x7FFFu + ((v.u >> 16) & 1u);
  return (u16)(r >> 16);
}

typedef const u32 __attribute__((address_space(1)))* gas_p;
typedef u32 __attribute__((address_space(3)))* las_p;
DEV void gl_lds16(const void* g, void* l) {
  __builtin_amdgcn_global_load_lds((gas_p)g, (las_p)l, 16, 0, 0);
}

// ---------------- mask prefix-scan: per batch, list of unmasked (mask==0) indices ----------------
__global__ __launch_bounds__(256) void maskscan_k(const int* __restrict__ mask,
    int* __restrict__ idx, int* __restrict__ cnt) {
  int b = blockIdx.x, tid = threadIdx.x;
  int lane = tid & 63, wv = tid >> 6;
  const int* mrow = mask + (size_t)b * NN;
  int base = tid * 8;
  int keep[8]; int local = 0;
  #pragma unroll
  for (int j = 0; j < 8; j++) { keep[j] = (mrow[base + j] == 0); local += keep[j]; }
  int incl = local;
  #pragma unroll
  for (int off = 1; off < 64; off <<= 1) {
    int v = __shfl_up(incl, off, 64);
    if (lane >= off) incl += v;
  }
  __shared__ int wsum[4];
  if (lane == 63) wsum[wv] = incl;
  __syncthreads();
  int wbase = 0;
  for (int w = 0; w < wv; w++) wbase += wsum[w];
  int pos = wbase + incl - local;
  #pragma unroll
  for (int j = 0; j < 8; j++) if (keep[j]) idx[(size_t)b * NN + pos++] = base + j;
  if (tid == 255) cnt[b] = wbase + incl;
}

// ---------------- fused LN + gather: xcomp[b][j] = LN(x[b][idx[b][j]]); pad rows zeroed ----------------
__global__ __launch_bounds__(256) void ln_gather_k(const float* __restrict__ x,
    const int* __restrict__ idx, const int* __restrict__ cnt, u16* __restrict__ xcomp) {
  int b = blockIdx.y, j = blockIdx.x, tid = threadIdx.x;
  int c = cnt[b];
  if (j >= ((c + 127) & ~127)) return;
  ushort4* orow = (ushort4*)(xcomp + ((size_t)b * NN + j) * DD);
  if (j >= c) { orow[tid] = make_ushort4(0, 0, 0, 0); return; }
  int src = idx[(size_t)b * NN + j];
  const float4* rp = (const float4*)(x + ((size_t)b * NN + src) * DD);
  float4 v = rp[tid];
  float s = v.x + v.y + v.z + v.w;
  float s2 = v.x*v.x + v.y*v.y + v.z*v.z + v.w*v.w;
  #pragma unroll
  for (int off = 32; off >= 1; off >>= 1) {
    s  += __shfl_xor(s, off, 64);
    s2 += __shfl_xor(s2, off, 64);
  }
  __shared__ float red[8];
  int wv = tid >> 6;
  if ((tid & 63) == 0) { red[wv] = s; red[4 + wv] = s2; }
  __syncthreads();
  s  = red[0] + red[1] + red[2] + red[3];
  s2 = red[4] + red[5] + red[6] + red[7];
  float mu = s * (1.f / DD);
  float var = s2 * (1.f / DD) - mu * mu;
  float rstd = rsqrtf(var + 1e-5f);
  orow[tid] = make_ushort4(f2bf((v.x - mu) * rstd), f2bf((v.y - mu) * rstd),
                           f2bf((v.z - mu) * rstd), f2bf((v.w - mu) * rstd));
}

// ---------------- LayerNorm over rows of 1024 (latent path) ----------------
template<bool OUTF32>
__global__ __launch_bounds__(256) void ln_rows_k(const float* __restrict__ in,
    const float* __restrict__ w, const float* __restrict__ bias, void* __restrict__ out) {
  int row = blockIdx.x;
  int tid = threadIdx.x;
  const float4* rp = (const float4*)(in + (size_t)row * DD);
  float4 x = rp[tid];
  float s = x.x + x.y + x.z + x.w;
  float s2 = x.x*x.x + x.y*x.y + x.z*x.z + x.w*x.w;
  #pragma unroll
  for (int off = 32; off >= 1; off >>= 1) {
    s  += __shfl_xor(s, off, 64);
    s2 += __shfl_xor(s2, off, 64);
  }
  __shared__ float red[8];
  int wv = tid >> 6;
  if ((tid & 63) == 0) { red[wv] = s; red[4 + wv] = s2; }
  __syncthreads();
  s  = red[0] + red[1] + red[2] + red[3];
  s2 = red[4] + red[5] + red[6] + red[7];
  float mu = s * (1.f / DD);
  float var = s2 * (1.f / DD) - mu * mu;
  float rstd = rsqrtf(var + 1e-5f);
  float y[4] = {x.x, x.y, x.z, x.w};
  int col = tid * 4;
  #pragma unroll
  for (int j = 0; j < 4; j++)
    y[j] = (y[j] - mu) * rstd * w[col + j] + bias[col + j];
  if (OUTF32) {
    float4 o = {y[0], y[1], y[2], y[3]};
    ((float4*)out)[(size_t)row * (DD/4) + tid] = o;
  } else {
    ushort4 o = make_ushort4(f2bf(y[0]), f2bf(y[1]), f2bf(y[2]), f2bf(y[3]));
    ((ushort4*)out)[(size_t)row * (DD/4) + tid] = o;
  }
}

// ---------------- lat init: broadcast latents over batch ----------------
__global__ __launch_bounds__(256) void lat_init_k(const float* __restrict__ latents, float* __restrict__ lat) {
  int idx = blockIdx.x * 256 + threadIdx.x;
  ((float4*)lat)[idx] = ((const float4*)latents)[idx & (LL * DD / 4 - 1)];
}

// ---------------- zero small buffer ----------------
__global__ void zero_k(float* __restrict__ p, int n) {
  int i = blockIdx.x * 256 + threadIdx.x;
  if (i < n) p[i] = 0.f;
}

// ---------------- ALL weight transposes for ALL depths + kv bias GEMVs, one launch ----------------
// per-depth id ranges: [0,512) Wq ; [512,1536) Wkv (+scaled copy + bias) ; [1536,2048) Wo
//                      [2048,6144) W1 ; [6144,10240) W2
__global__ void transpall_k(const float* __restrict__ WqA, const float* __restrict__ WkvA,
    const float* __restrict__ WoA, const float* __restrict__ W1A, const float* __restrict__ W2A,
    const float* __restrict__ lnwA, const float* __restrict__ lnbA,
    u16* __restrict__ WqkvTA, u16* __restrict__ WkvTfA, u16* __restrict__ WoTA,
    u16* __restrict__ W1TA, u16* __restrict__ W2TA, float* __restrict__ biaskvA) {
  __shared__ float t[32][33];
  __shared__ float bred[8][32];
  int gid = blockIdx.x;
  int depth = gid / 10240;
  int id = gid % 10240;
  const float* in; u16* o1; int R, C, c0, r0;
  bool iskv = false;
  if (id < 512)       { in = WqA  + (size_t)depth*1024*512;  R = 1024; C = 512;  int l = id;        c0 = (l % 16) * 32;  r0 = (l / 16) * 32;  o1 = WqkvTA + (size_t)depth*1536*1024; }
  else if (id < 1536) { in = WkvA + (size_t)depth*1024*1024; R = 1024; C = 1024; int l = id - 512;  c0 = (l % 32) * 32;  r0 = (l / 32) * 32;  o1 = WqkvTA + (size_t)depth*1536*1024 + 512*1024; iskv = true; }
  else if (id < 2048) { in = WoA  + (size_t)depth*512*1024;  R = 512;  C = 1024; int l = id - 1536; c0 = (l % 32) * 32;  r0 = (l / 32) * 32;  o1 = WoTA + (size_t)depth*1024*512; }
  else if (id < 6144) { in = W1A  + (size_t)depth*1024*4096; R = 1024; C = 4096; int l = id - 2048; c0 = (l % 128) * 32; r0 = (l / 128) * 32; o1 = W1TA + (size_t)depth*4096*1024; }
  else                { in = W2A  + (size_t)depth*4096*1024; R = 4096; C = 1024; int l = id - 6144; c0 = (l % 32) * 32;  r0 = (l / 32) * 32;  o1 = W2TA + (size_t)depth*1024*4096; }
  int tx = threadIdx.x, ty = threadIdx.y; // 32 x 8
  #pragma unroll
  for (int j = 0; j < 4; j++)
    t[ty + j*8][tx] = in[(size_t)(r0 + ty + j*8) * C + c0 + tx];
  __syncthreads();
  #pragma unroll
  for (int j = 0; j < 4; j++)
    o1[(size_t)(c0 + ty + j*8) * R + r0 + tx] = f2bf(t[tx][ty + j*8]);
  if (iskv) {
    const float* lnw = lnwA + depth * 1024;
    const float* lnb = lnbA + depth * 1024;
    u16* WkvTf = WkvTfA + (size_t)depth*1024*1024;
    float sc = lnw[r0 + tx];
    #pragma unroll
    for (int j = 0; j < 4; j++)
      WkvTf[(size_t)(c0 + ty + j*8) * 1024 + r0 + tx] = f2bf(t[tx][ty + j*8] * sc);
    float partial = 0.f;
    #pragma unroll
    for (int rr = 0; rr < 4; rr++)
      partial += lnb[r0 + ty + rr*8] * t[ty + rr*8][tx];
    bred[ty][tx] = partial;
    __syncthreads();
    if (ty == 0) {
      float sum = 0.f;
      #pragma unroll
      for (int w = 0; w < 8; w++) sum += bred[w][tx];
      atomicAdd(&biaskvA[depth*1024 + c0 + tx], sum);
    }
  }
}

// ---------------- fused GEMM launch: kv (2048 swizzled blocks) + latent qkv (96 blocks) ----------
// kv:  kvx[16*2048][1024] = xcomp @ WkvTf^T + biaskv, early-exit past cnt[b]
// qkv: qkv[1024][1536]    = lnl @ WqkvT^T
__global__ __launch_bounds__(256) void gemm_fused_k(
    const u16* __restrict__ xcomp, const u16* __restrict__ WkvTf, u16* __restrict__ kvx,
    const float* __restrict__ bias, const int* __restrict__ cnt,
    const u16* __restrict__ lnl, const u16* __restrict__ WqkvT, u16* __restrict__ qkv) {
  __shared__ __align__(16) u16 As[128 * 32];
  __shared__ __align__(16) u16 Bs[128 * 32];
  int id = blockIdx.x;
  int tid = threadIdx.x;
  int wv = tid >> 6, lane = tid & 63;
  const u16 *A, *B; u16* C; int N; bool dobias;
  int m0, n0;
  if (id < 2048) {
    int xg = id & 7, t = id >> 3;
    int mtile = xg * 32 + (t >> 3);
    n0 = (t & 7) * 128;
    int batch = mtile >> 4;
    int ml = (mtile & 15) * 128;
    if (ml >= cnt[batch]) return;
    m0 = batch * NN + ml;
    A = xcomp; B = WkvTf; C = kvx; N = 1024; dobias = true;
  } else {
    int l = id - 2048;            // 8 mtiles x 12 ntiles
    m0 = (l / 12) * 128; n0 = (l % 12) * 128;
    A = lnl; B = WqkvT; C = qkv; N = 1536; dobias = false;
  }
  const int K = 1024;
  int srow = wv * 16 + (lane >> 2);
  int scol = (lane & 3) * 8;
  const u16* gA0 = A + (size_t)(m0 + srow) * K + scol;
  const u16* gA1 = A + (size_t)(m0 + 64 + srow) * K + scol;
  const u16* gB0 = B + (size_t)(n0 + srow) * K + scol;
  const u16* gB1 = B + (size_t)(n0 + 64 + srow) * K + scol;
  u16* lA0 = &As[srow * 32 + scol];
  u16* lA1 = &As[(64 + srow) * 32 + scol];
  u16* lB0 = &Bs[srow * 32 + scol];
  u16* lB1 = &Bs[(64 + srow) * 32 + scol];
  int wm = (wv & 1) * 64, wn = (wv >> 1) * 64;
  int fr = lane & 15, fq = (lane >> 4) * 8;
  f4 acc[4][4];
  #pragma unroll
  for (int mi = 0; mi < 4; mi++)
    #pragma unroll
    for (int ni = 0; ni < 4; ni++) acc[mi][ni] = f4{0.f, 0.f, 0.f, 0.f};

  for (int k0 = 0; k0 < K; k0 += 32) {
    gl_lds16(gA0 + k0, lA0);
    gl_lds16(gA1 + k0, lA1);
    gl_lds16(gB0 + k0, lB0);
    gl_lds16(gB1 + k0, lB1);
    __syncthreads();
    short8 af[4], bfr[4];
    #pragma unroll
    for (int mi = 0; mi < 4; mi++)
      af[mi] = *(const short8*)&As[(wm + mi*16 + fr) * 32 + fq];
    #pragma unroll
    for (int ni = 0; ni < 4; ni++)
      bfr[ni] = *(const short8*)&Bs[(wn + ni*16 + fr) * 32 + fq];
    #pragma unroll
    for (int mi = 0; mi < 4; mi++)
      #pragma unroll
      for (int ni = 0; ni < 4; ni++)
        acc[mi][ni] = __builtin_amdgcn_mfma_f32_16x16x32_bf16(af[mi], bfr[ni], acc[mi][ni], 0, 0, 0);
    __syncthreads();
  }
  int er = (lane >> 4) * 4;
  int ec = lane & 15;
  #pragma unroll
  for (int mi = 0; mi < 4; mi++) {
    #pragma unroll
    for (int ni = 0; ni < 4; ni++) {
      int col = n0 + wn + ni*16 + ec;
      float bv = dobias ? bias[col] : 0.f;
      #pragma unroll
      for (int r = 0; r < 4; r++) {
        int row = m0 + wm + mi*16 + er + r;
        C[(size_t)row * N + col] = f2bf(acc[mi][ni][r] + bv);
      }
    }
  }
}

// ---------------- GEMM 128x128 gelu epilogue (W1: M=1024 N=4096 K=1024) ----------------
__global__ __launch_bounds__(256) void gemm_gelu_k(const u16* __restrict__ A, const u16* __restrict__ Bm,
    u16* __restrict__ C, int M, int N, int K) {
  __shared__ __align__(16) u16 As[128 * 32];
  __shared__ __align__(16) u16 Bs[128 * 32];
  int tid = threadIdx.x;
  int wv = tid >> 6, lane = tid & 63;
  int m0 = blockIdx.y * 128, n0 = blockIdx.x * 128;
  int srow = wv * 16 + (lane >> 2);
  int scol = (lane & 3) * 8;
  const u16* gA0 = A + (size_t)(m0 + srow) * K + scol;
  const u16* gA1 = A + (size_t)(m0 + 64 + srow) * K + scol;
  const u16* gB0 = Bm + (size_t)(n0 + srow) * K + scol;
  const u16* gB1 = Bm + (size_t)(n0 + 64 + srow) * K + scol;
  u16* lA0 = &As[srow * 32 + scol];
  u16* lA1 = &As[(64 + srow) * 32 + scol];
  u16* lB0 = &Bs[srow * 32 + scol];
  u16* lB1 = &Bs[(64 + srow) * 32 + scol];
  int wm = (wv & 1) * 64, wn = (wv >> 1) * 64;
  int fr = lane & 15, fq = (lane >> 4) * 8;
  f4 acc[4][4];
  #pragma unroll
  for (int mi = 0; mi < 4; mi++)
    #pragma unroll
    for (int ni = 0; ni < 4; ni++) acc[mi][ni] = f4{0.f, 0.f, 0.f, 0.f};

  for (int k0 = 0; k0 < K; k0 += 32) {
    gl_lds16(gA0 + k0, lA0);
    gl_lds16(gA1 + k0, lA1);
    gl_lds16(gB0 + k0, lB0);
    gl_lds16(gB1 + k0, lB1);
    __syncthreads();
    short8 af[4], bfr[4];
    #pragma unroll
    for (int mi = 0; mi < 4; mi++)
      af[mi] = *(const short8*)&As[(wm + mi*16 + fr) * 32 + fq];
    #pragma unroll
    for (int ni = 0; ni < 4; ni++)
      bfr[ni] = *(const short8*)&Bs[(wn + ni*16 + fr) * 32 + fq];
    #pragma unroll
    for (int mi = 0; mi < 4; mi++)
      #pragma unroll
      for (int ni = 0; ni < 4; ni++)
        acc[mi][ni] = __builtin_amdgcn_mfma_f32_16x16x32_bf16(af[mi], bfr[ni], acc[mi][ni], 0, 0, 0);
    __syncthreads();
  }
  int er = (lane >> 4) * 4;
  int ec = lane & 15;
  #pragma unroll
  for (int mi = 0; mi < 4; mi++)
    #pragma unroll
    for (int ni = 0; ni < 4; ni++) {
      int col = n0 + wn + ni*16 + ec;
      #pragma unroll
      for (int r = 0; r < 4; r++) {
        int row = m0 + wm + mi*16 + er + r;
        float v = acc[mi][ni][r];
        v = 0.5f * v * (1.f + erff(v * 0.70710678118654752f));
        C[(size_t)row * N + col] = f2bf(v);
      }
    }
}

// ---------------- split-K GEMM 128x128, fp32 atomicAdd epilogue (C pre-holds residual) ----------------
__global__ __launch_bounds__(256) void gemmsk_k(const u16* __restrict__ A, const u16* __restrict__ Bm,
    float* __restrict__ C, int M, int N, int K, int Kc) {
  __shared__ __align__(16) u16 As[128 * 32];
  __shared__ __align__(16) u16 Bs[128 * 32];
  int tid = threadIdx.x;
  int wv = tid >> 6, lane = tid & 63;
  int m0 = blockIdx.y * 128, n0 = blockIdx.x * 128;
  int kb = blockIdx.z * Kc;
  int srow = wv * 16 + (lane >> 2);
  int scol = (lane & 3) * 8;
  const u16* gA0 = A + (size_t)(m0 + srow) * K + kb + scol;
  const u16* gA1 = A + (size_t)(m0 + 64 + srow) * K + kb + scol;
  const u16* gB0 = Bm + (size_t)(n0 + srow) * K + kb + scol;
  const u16* gB1 = Bm + (size_t)(n0 + 64 + srow) * K + kb + scol;
  u16* lA0 = &As[srow * 32 + scol];
  u16* lA1 = &As[(64 + srow) * 32 + scol];
  u16* lB0 = &Bs[srow * 32 + scol];
  u16* lB1 = &Bs[(64 + srow) * 32 + scol];
  int wm = (wv & 1) * 64, wn = (wv >> 1) * 64;
  int fr = lane & 15, fq = (lane >> 4) * 8;
  f4 acc[4][4];
  #pragma unroll
  for (int mi = 0; mi < 4; mi++)
    #pragma unroll
    for (int ni = 0; ni < 4; ni++) acc[mi][ni] = f4{0.f, 0.f, 0.f, 0.f};

  for (int k0 = 0; k0 < Kc; k0 += 32) {
    gl_lds16(gA0 + k0, lA0);
    gl_lds16(gA1 + k0, lA1);
    gl_lds16(gB0 + k0, lB0);
    gl_lds16(gB1 + k0, lB1);
    __syncthreads();
    short8 af[4], bfr[4];
    #pragma unroll
    for (int mi = 0; mi < 4; mi++)
      af[mi] = *(const short8*)&As[(wm + mi*16 + fr) * 32 + fq];
    #pragma unroll
    for (int ni = 0; ni < 4; ni++)
      bfr[ni] = *(const short8*)&Bs[(wn + ni*16 + fr) * 32 + fq];
    #pragma unroll
    for (int mi = 0; mi < 4; mi++)
      #pragma unroll
      for (int ni = 0; ni < 4; ni++)
        acc[mi][ni] = __builtin_amdgcn_mfma_f32_16x16x32_bf16(af[mi], bfr[ni], acc[mi][ni], 0, 0, 0);
    __syncthreads();
  }
  int er = (lane >> 4) * 4;
  int ec = lane & 15;
  #pragma unroll
  for (int mi = 0; mi < 4; mi++)
    #pragma unroll
    for (int ni = 0; ni < 4; ni++) {
      int col = n0 + wn + ni*16 + ec;
      #pragma unroll
      for (int r = 0; r < 4; r++) {
        int row = m0 + wm + mi*16 + er + r;
        atomicAdd(&C[(size_t)row * N + col], acc[mi][ni][r]);
      }
    }
}

// ---------------- flash attention, split over keys: 2 blocks per (b,h) ----------------
// qkv: [1024][1536] = [q(512) | k_lat(512) | v_lat(512)]; kvx: compacted [16*2048][1024]
__global__ __launch_bounds__(256) void attn_part_k(const u16* __restrict__ qkv,
    const u16* __restrict__ kvx, const int* __restrict__ cnt,
    float* __restrict__ opart, float* __restrict__ mlpart) {
  int id = blockIdx.x;          // 256
  int b = id >> 4;
  int h = (id >> 1) & 7;
  int half = id & 1;
  int tid = threadIdx.x;
  int wv = tid >> 6, lane = tid & 63;
  int fr = lane & 15, fq8 = (lane >> 4) * 8;
  int c = cnt[b];
  int nt = (c + 63) >> 6;       // x-key tiles; tile nt is the latent tile
  int T = nt + 1;
  int t0 = half ? (T >> 1) : 0;
  int t1 = half ? T : (T >> 1);

  __shared__ __align__(16) u16 ks[64 * 88];
  __shared__ __align__(16) u16 vs[64 * 88];
  __shared__ __align__(16) u16 ps[4][16 * 88];
  __shared__ float smask[64];

  const u16* qp = qkv + (size_t)(b * LL + wv * 16 + fr) * 1536 + h * DHD;
  short8 aq0 = *(const short8*)(qp + fq8);
  short8 aq1 = *(const short8*)(qp + 32 + fq8);

  float m_i[4], l_i[4];
  f4 o[4];
  #pragma unroll
  for (int r = 0; r < 4; r++) { m_i[r] = -1e30f; l_i[r] = 0.f; }
  #pragma unroll
  for (int dt = 0; dt < 4; dt++) o[dt] = f4{0.f, 0.f, 0.f, 0.f};

  const float scale = 0.125f;

  for (int t = t0; t < t1; t++) {
    bool isLat = (t == nt);
    const u16* src;
    int rs;
    if (isLat) { src = qkv + (size_t)(b * LL) * 1536 + 512 + h * DHD; rs = 1536; }
    else       { src = kvx + (size_t)(b * NN + t * 64) * 1024 + h * DHD; rs = 1024; }
    __syncthreads();
    #pragma unroll
    for (int it = 0; it < 2; it++) {
      int cid = it * 256 + tid;
      int kr = cid >> 3, c8 = (cid & 7) * 8;
      int4 kvv = *(const int4*)(src + (size_t)kr * rs + c8);
      *(int4*)&ks[kr * 88 + c8] = kvv;
      int4 vvv = *(const int4*)(src + 512 + (size_t)kr * rs + c8);
      const u16* ve = (const u16*)&vvv;
      #pragma unroll
      for (int j = 0; j < 8; j++) vs[(c8 + j) * 88 + kr] = ve[j];
    }
    if (tid < 64)
      smask[tid] = (isLat || (t * 64 + tid < c)) ? 0.f : -1e30f;
    __syncthreads();

    f4 sim[4];
    #pragma unroll
    for (int ct = 0; ct < 4; ct++) {
      short8 b0 = *(const short8*)&ks[(ct*16 + fr) * 88 + fq8];
      short8 b1 = *(const short8*)&ks[(ct*16 + fr) * 88 + 32 + fq8];
      f4 s = f4{0.f, 0.f, 0.f, 0.f};
      s = __builtin_amdgcn_mfma_f32_16x16x32_bf16(aq0, b0, s, 0, 0, 0);
      s = __builtin_amdgcn_mfma_f32_16x16x32_bf16(aq1, b1, s, 0, 0, 0);
      float mk = smask[ct*16 + fr];
      #pragma unroll
      for (int r = 0; r < 4; r++) s[r] = s[r] * scale + mk;
      sim[ct] = s;
    }
    float mnew[4], alpha[4], p[4][4];
    #pragma unroll
    for (int r = 0; r < 4; r++) {
      float mx = fmaxf(fmaxf(sim[0][r], sim[1][r]), fmaxf(sim[2][r], sim[3][r]));
      #pragma unroll
      for (int off = 8; off >= 1; off >>= 1) mx = fmaxf(mx, __shfl_xor(mx, off, 16));
      mnew[r] = fmaxf(m_i[r], mx);
      alpha[r] = __expf(m_i[r] - mnew[r]);
      m_i[r] = mnew[r];
      float ssum = 0.f;
      #pragma unroll
      for (int ct = 0; ct < 4; ct++) { float e = __expf(sim[ct][r] - mnew[r]); p[ct][r] = e; ssum += e; }
      #pragma unroll
      for (int off = 8; off >= 1; off >>= 1) ssum += __shfl_xor(ssum, off, 16);
      l_i[r] = l_i[r] * alpha[r] + ssum;
    }
    #pragma unroll
    for (int ct = 0; ct < 4; ct++)
      #pragma unroll
      for (int r = 0; r < 4; r++)
        ps[wv][((lane>>4)*4 + r) * 88 + ct*16 + fr] = f2bf(p[ct][r]);
    #pragma unroll
    for (int dt = 0; dt < 4; dt++)
      #pragma unroll
      for (int r = 0; r < 4; r++) o[dt][r] *= alpha[r];
    short8 pa0 = *(const short8*)&ps[wv][fr * 88 + fq8];
    short8 pa1 = *(const short8*)&ps[wv][fr * 88 + 32 + fq8];
    #pragma unroll
    for (int dt = 0; dt < 4; dt++) {
      short8 bv0 = *(const short8*)&vs[(dt*16 + fr) * 88 + fq8];
      short8 bv1 = *(const short8*)&vs[(dt*16 + fr) * 88 + 32 + fq8];
      o[dt] = __builtin_amdgcn_mfma_f32_16x16x32_bf16(pa0, bv0, o[dt], 0, 0, 0);
      o[dt] = __builtin_amdgcn_mfma_f32_16x16x32_bf16(pa1, bv1, o[dt], 0, 0, 0);
    }
  }
  #pragma unroll
  for (int dt = 0; dt < 4; dt++)
    #pragma unroll
    for (int r = 0; r < 4; r++) {
      int row = wv * 16 + (lane>>4)*4 + r;
      int col = dt*16 + fr;
      opart[((size_t)id * 64 + row) * 64 + col] = o[dt][r];
    }
  if (fr == 0) {
    #pragma unroll
    for (int r = 0; r < 4; r++) {
      int row = wv * 16 + (lane>>4)*4 + r;
      mlpart[id * 128 + row * 2]     = m_i[r];
      mlpart[id * 128 + row * 2 + 1] = l_i[r];
    }
  }
}

// ---------------- combine the two key-halves ----------------
__global__ __launch_bounds__(256) void attn_comb_k(const float* __restrict__ opart,
    const float* __restrict__ mlpart, u16* __restrict__ out) {
  int bh = blockIdx.x;          // 128
  int b = bh >> 3, h = bh & 7;
  int id0 = bh * 2, id1 = bh * 2 + 1;
  int tid = threadIdx.x;
  int row = tid >> 2;
  int c0 = (tid & 3) * 16;
  float m0 = mlpart[id0 * 128 + row * 2], l0 = mlpart[id0 * 128 + row * 2 + 1];
  float m1 = mlpart[id1 * 128 + row * 2], l1 = mlpart[id1 * 128 + row * 2 + 1];
  float m = fmaxf(m0, m1);
  float a0 = __expf(m0 - m), a1 = __expf(m1 - m);
  float rl = 1.f / (l0 * a0 + l1 * a1);
  const float4* p0 = (const float4*)(opart + ((size_t)id0 * 64 + row) * 64 + c0);
  const float4* p1 = (const float4*)(opart + ((size_t)id1 * 64 + row) * 64 + c0);
  u16* op = out + ((size_t)(b * LL + row)) * II + h * DHD + c0;
  #pragma unroll
  for (int j = 0; j < 4; j++) {
    float4 v0 = p0[j], v1 = p1[j];
    op[j*4 + 0] = f2bf((v0.x * a0 + v1.x * a1) * rl);
    op[j*4 + 1] = f2bf((v0.y * a0 + v1.y * a1) * rl);
    op[j*4 + 2] = f2bf((v0.z * a0 + v1.z * a1) * rl);
    op[j*4 + 3] = f2bf((v0.w * a0 + v1.w * a1) * rl);
  }
}

extern "C" void kernel_launch(void* const* d_in, const int* in_sizes, int n_in,
                              void* d_out, int out_size, void* d_ws, size_t ws_size,
                              hipStream_t stream) {
  (void)in_sizes; (void)n_in; (void)out_size; (void)ws_size;
  const float* x       = (const float*)d_in[0];
  const int*   mask    = (const int*)d_in[1];
  const float* latents = (const float*)d_in[2];
  const float* ln_m_w  = (const float*)d_in[3];
  const float* ln_m_b  = (const float*)d_in[4];
  const float* ln_l_w  = (const float*)d_in[5];
  const float* ln_l_b  = (const float*)d_in[6];
  const float* Wq      = (const float*)d_in[7];
  const float* Wkv     = (const float*)d_in[8];
  const float* Wo      = (const float*)d_in[9];
  const float* ff_ln_w = (const float*)d_in[10];
  const float* ff_ln_b = (const float*)d_in[11];
  const float* W1      = (const float*)d_in[12];
  const float* W2      = (const float*)d_in[13];
  const float* norm_w  = (const float*)d_in[14];
  const float* norm_b  = (const float*)d_in[15];
  float* out = (float*)d_out;

  char* ws = (char*)d_ws;
  size_t off = 0;
  auto alloc = [&](size_t bytes) -> void* {
    void* p = ws + off; off += (bytes + 255) & ~(size_t)255; return p;
  };
  u16* xcomp = (u16*)alloc((size_t)32768 * 1024 * 2);
  u16* kvx   = (u16*)alloc((size_t)32768 * 1024 * 2);
  int* idxb  = (int*)alloc((size_t)32768 * 4);
  int* cnt   = (int*)alloc(64);
  float* lat = (float*)alloc((size_t)1024 * 1024 * 4);
  u16* lnl   = (u16*)alloc((size_t)1024 * 1024 * 2);
  u16* latn  = (u16*)alloc((size_t)1024 * 1024 * 2);
  u16* qkv   = (u16*)alloc((size_t)1024 * 1536 * 2);
  u16* aout  = (u16*)alloc((size_t)1024 * 512 * 2);
  u16* hf    = (u16*)alloc((size_t)1024 * 4096 * 2);
  float* opart  = (float*)alloc((size_t)256 * 64 * 64 * 4);
  float* mlpart = (float*)alloc((size_t)256 * 128 * 4);
  u16* WqkvT = (u16*)alloc((size_t)DEPTHC * 1536 * 1024 * 2);
  u16* WkvTf = (u16*)alloc((size_t)DEPTHC * 1024 * 1024 * 2);
  u16* WoT   = (u16*)alloc((size_t)DEPTHC * 1024 * 512 * 2);
  u16* W1T   = (u16*)alloc((size_t)DEPTHC * 4096 * 1024 * 2);
  u16* W2T   = (u16*)alloc((size_t)DEPTHC * 1024 * 4096 * 2);
  float* biaskv_all = (float*)alloc(DEPTHC * 1024 * 4);

  // pre-loop: compaction, LN-gather, lat init, bias zero, ALL weight transposes (6 depths)
  maskscan_k<<<16, 256, 0, stream>>>(mask, idxb, cnt);
  ln_gather_k<<<dim3(2048, 16), 256, 0, stream>>>(x, idxb, cnt, xcomp);
  lat_init_k<<<1024, 256, 0, stream>>>(latents, lat);
  zero_k<<<24, 256, 0, stream>>>(biaskv_all, DEPTHC * 1024);
  transpall_k<<<DEPTHC * 10240, dim3(32, 8), 0, stream>>>(
      Wq, Wkv, Wo, W1, W2, ln_m_w, ln_m_b,
      WqkvT, WkvTf, WoT, W1T, W2T, biaskv_all);

  for (int i = 0; i < DEPTHC; i++) {
    ln_rows_k<false><<<1024, 256, 0, stream>>>(lat, ln_l_w + i*1024, ln_l_b + i*1024, lnl);
    gemm_fused_k<<<2144, 256, 0, stream>>>(
        xcomp, WkvTf + (size_t)i*1024*1024, kvx, biaskv_all + i*1024, cnt,
        lnl, WqkvT + (size_t)i*1536*1024, qkv);
    attn_part_k<<<256, 256, 0, stream>>>(qkv, kvx, cnt, opart, mlpart);
    attn_comb_k<<<128, 256, 0, stream>>>(opart, mlpart, aout);
    gemmsk_k<<<dim3(8, 8, 4), 256, 0, stream>>>(aout, WoT + (size_t)i*1024*512, lat, 1024, 1024, 512, 128);
    ln_rows_k<false><<<1024, 256, 0, stream>>>(lat, ff_ln_w + i*1024, ff_ln_b + i*1024, latn);
    gemm_gelu_k<<<dim3(32, 8), 256, 0, stream>>>(latn, W1T + (size_t)i*4096*1024, hf, 1024, 4096, 1024);
    gemmsk_k<<<dim3(8, 8, 4), 256, 0, stream>>>(hf, W2T + (size_t)i*1024*4096, lat, 1024, 1024, 4096, 1024);
  }
  ln_rows_k<true><<<1024, 256, 0, stream>>>(lat, norm_w, norm_b, out);
}